// Round 1
// baseline (451.045 us; speedup 1.0000x reference)
//
#include <hip/hip_runtime.h>
#include <cstdint>

#define B_IMG   8
#define NCAND   36720
#define PD      85
#define NCLS    80
#define KC      512
#define MAXDET  300
#define NBUCK   2048
#define CANDCAP 1024      // gathered count is ~512 + one-bucket (<~40): 1024 is safe

// G (fp32, level-major) float offsets: L1[8][9216][64] | L2[8][2304][64] | L3[8][576][64] | L4[8][144][64]
#define G2_OFF 4718592
#define G3_OFF 5898240
#define G4_OFF 6193152
#define G_TOT  6266880

typedef unsigned int u32;
typedef unsigned long long u64;

__device__ __forceinline__ float leaky(float x){ return x >= 0.f ? x : 0.01f*x; }

__device__ __forceinline__ u64 shfl_u64(u64 v, int lane){
  int lo = __shfl((int)(u32)(v & 0xFFFFFFFFull), lane, 64);
  int hi = __shfl((int)(u32)(v >> 32), lane, 64);
  return ((u64)(u32)hi << 32) | (u64)(u32)lo;
}
__device__ __forceinline__ u64 shfl_xor_u64(u64 v, int mask){
  int lo = __shfl_xor((int)(u32)(v & 0xFFFFFFFFull), mask, 64);
  int hi = __shfl_xor((int)(u32)(v >> 32), mask, 64);
  return ((u64)(u32)hi << 32) | (u64)(u32)lo;
}

// ---------------- K1: two-phase score: obj-filter -> class-scan survivors only ----
__global__ __launch_bounds__(256) void k_score(const float* __restrict__ preds,
    u32* __restrict__ sbits, int* __restrict__ clsArr, u32* __restrict__ hist){
  __shared__ u32   sl_lane[4][64];
  __shared__ float sl_obj[4][64];
  __shared__ u32   sl_res[4][64];
  __shared__ u32   sl_cls[4][64];
  const int img  = blockIdx.y;
  const int wv   = threadIdx.x >> 6;
  const int lane = threadIdx.x & 63;
  const int base = (blockIdx.x*4 + wv)*64;
  const int ci   = base + lane;
  const bool inb = ci < NCAND;
  float obj = 0.f;
  if (inb) obj = preds[((long)img*NCAND + ci)*PD + 4];
  const bool pass = obj > 0.596f;
  u64 mask = __ballot(pass);
  int cnt  = __popcll(mask);
  int rank = __popcll(mask & ((1ull << lane) - 1ull));
  if (pass){ sl_lane[wv][rank] = (u32)lane; sl_obj[wv][rank] = obj; }
  const int q = lane & 3;
  for (int r0 = 0; r0 < cnt; r0 += 16){
    int idx = r0 + (lane >> 2);
    if (idx < cnt){
      u32 sl = sl_lane[wv][idx];
      float obj2 = sl_obj[wv][idx];
      const float* p2 = preds + ((long)img*NCAND + base + (int)sl)*PD + 5 + q;
      u64 best = 0ull;
      #pragma unroll
      for (int k = 0; k < 20; k++){
        float v = p2[4*k] * obj2;                       // exact ref: cls*obj
        u64 key = ((u64)__float_as_uint(v) << 32) | (u64)(~(u32)(q + 4*k));
        if (key > best) best = key;                     // first max wins
      }
      u64 o1 = shfl_xor_u64(best, 1); if (o1 > best) best = o1;
      u64 o2 = shfl_xor_u64(best, 2); if (o2 > best) best = o2;
      if (q == 0){
        u32 bits = (u32)(best >> 32);
        sl_res[wv][sl] = (__uint_as_float(bits) > 0.596f) ? bits : 0u;
        sl_cls[wv][sl] = ~(u32)(best & 0xFFFFFFFFull);
      }
    }
  }
  if (inb){
    u32 out = pass ? sl_res[wv][lane] : 0u;             // valid scores in (0.596,1)
    sbits[(long)img*NCAND + ci] = out;
    if (pass) clsArr[(long)img*NCAND + ci] = (int)sl_cls[wv][lane];
    if (out) atomicAdd(&hist[img*NBUCK + ((out - 0x3F000000u) >> 12)], 1u);
  }
}

// ---------------- K2: per-image bit-threshold covering top-512 ----------------
__global__ __launch_bounds__(64) void k_thresh(const u32* __restrict__ hist,
                                               u32* __restrict__ thr){
  const int img = blockIdx.x;
  const int lane = threadIdx.x;
  const u32* h = hist + img*NBUCK;
  u32 acc = 0; u32 result = 0x3F000000u; bool found = false;
  for (int g = NBUCK/64 - 1; g >= 0 && !found; g--){
    u32 v = h[g*64 + lane];
    u32 s = v;
    #pragma unroll
    for (int off = 1; off < 64; off <<= 1){
      u32 t = __shfl_down(s, off, 64);
      s += (lane + off < 64) ? t : 0u;
    }
    u64 mask = __ballot(acc + s >= KC);
    if (mask){
      int hl = 63 - __clzll(mask);
      result = 0x3F000000u + ((u32)(g*64 + hl) << 12);
      found = true;
    }
    acc += __shfl(s, 0, 64);
  }
  if (lane == 0) thr[img] = result;
}

// ---------------- K3: gather candidates >= threshold as sortable keys ----------------
__global__ __launch_bounds__(256) void k_gather(const u32* __restrict__ sbits,
    const u32* __restrict__ thr, u32* __restrict__ cnt, u64* __restrict__ cand){
  int img = blockIdx.y;
  int n = blockIdx.x*256 + threadIdx.x;
  if (n >= NCAND) return;
  u32 bits = sbits[(long)img*NCAND + n];
  if (bits && bits >= thr[img]){
    u32 pos = atomicAdd(&cnt[img], 1u);
    if (pos < CANDCAP)
      cand[(long)img*CANDCAP + pos] = ((u64)bits << 32) | (u64)(0xFFFFFFFFu - (u32)n);
  }
}

// ---------------- K4: fused NMS: rank -> decode -> IOU matrix -> greedy -> compact ----
__global__ __launch_bounds__(512) void k_nms(const float* __restrict__ preds,
    const int* __restrict__ clsArr, const u64* __restrict__ cand,
    const u32* __restrict__ cnt, float* __restrict__ selbox, u32* __restrict__ selcnt){
#pragma clang fp contract(off)
  __shared__ __align__(16) u64 keys[CANDCAP];      // 8 KB
  __shared__ float4 cbs[KC];                       // 8 KB  class-offset boxes
  __shared__ float4 obs[KC];                       // 8 KB  original boxes
  __shared__ u64 lrows[KC*8];                      // 32 KB suppression matrix
  __shared__ u64 kmask[8];
  __shared__ u64 keepw[8];
  const int img = blockIdx.x;
  const int tid = threadIdx.x;
  const int M = min((int)cnt[img], CANDCAP);
  keys[tid]       = (tid < M)       ? cand[(long)img*CANDCAP + tid]       : 0ull;
  keys[tid + 512] = (tid + 512 < M) ? cand[(long)img*CANDCAP + tid + 512] : 0ull;
  cbs[tid] = make_float4(-4e8f, -4e8f, -4e8f, -4e8f);   // zero-area -> iou 0
  obs[tid] = make_float4(0.f, 0.f, 0.f, 0.f);
  if (tid < 8) kmask[tid] = 0ull;
  __syncthreads();
  // ---- rank by count (desc): rank = #{keys strictly greater} ----
  u64 k0 = keys[tid], k1 = keys[tid + 512];
  int r0 = 0, r1 = 0;
  const ulonglong2* kv = (const ulonglong2*)keys;
  for (int j = 0; j < CANDCAP/2; j++){              // wave-uniform b128 broadcast
    ulonglong2 kk = kv[j];
    r0 += (kk.x > k0) + (kk.y > k0);
    r1 += (kk.x > k1) + (kk.y > k1);
  }
  #pragma unroll
  for (int t = 0; t < 2; t++){
    u64 key = t ? k1 : k0;
    int rank = t ? r1 : r0;
    if ((key >> 32) != 0ull && rank < KC){
      u32 idxn = 0xFFFFFFFFu - (u32)(key & 0xFFFFFFFFull);
      const float* p = preds + ((long)img*NCAND + idxn)*PD;
      float cx = p[0], cy = p[1], w = p[2], h = p[3];
      float hw = w*0.5f, hh = h*0.5f;               // exact
      float X1 = cx-hw, Y1 = cy-hh, X2 = cx+hw, Y2 = cy+hh;
      float off = (float)clsArr[(long)img*NCAND + idxn] * 4096.0f;  // exact
      obs[rank] = make_float4(X1, Y1, X2, Y2);
      cbs[rank] = make_float4(X1+off, Y1+off, X2+off, Y2+off);
      atomicOr(&kmask[rank >> 6], 1ull << (rank & 63));
    }
  }
  __syncthreads();
  {
    const int i = tid;
    float4 bi = cbs[i];
    float areai = (bi.z - bi.x)*(bi.w - bi.y);
    for (int w = 0; w < 8; w++){
      u64 bits = 0ull;
      int jbase = w*64;
      for (int b = 0; b < 64; b++){
        int j = jbase + b;
        if (j > i){
          float4 bj = cbs[j];
          float areaj = (bj.z - bj.x)*(bj.w - bj.y);
          float ltx = fmaxf(bi.x, bj.x), lty = fmaxf(bi.y, bj.y);
          float rbx = fminf(bi.z, bj.z), rby = fminf(bi.w, bj.w);
          float ww = fmaxf(rbx - ltx, 0.f);
          float hh = fmaxf(rby - lty, 0.f);
          float inter = ww*hh;
          float iou = inter / (areai + areaj - inter + 1e-7f);  // exact ref op order
          if (iou > 0.45f) bits |= (1ull << b);
        }
      }
      lrows[i*8 + w] = bits;
    }
  }
  __syncthreads();
  // ---- greedy: wave 0, lane-local blocked update ----
  if (tid < 64){
    const int lane = tid;
    const int w = lane & 7;
    u64 kw_own = kmask[w];
    for (int b = 0; b < 8; b++){
      u64 kwb = shfl_u64(kw_own, b);
      for (int g = 0; g < 8; g++){
        u64 rdec[8], rown[8];
        #pragma unroll
        for (int k = 0; k < 8; k++){
          int i = b*64 + g*8 + k;
          rdec[k] = lrows[i*8 + b];
          rown[k] = lrows[i*8 + w];
        }
        #pragma unroll
        for (int k = 0; k < 8; k++){
          int il = g*8 + k;
          if ((kwb >> il) & 1ull){
            kwb    &= ~rdec[k];
            kw_own &= ~rown[k];
          }
        }
      }
    }
    if (lane < 8) keepw[lane] = kw_own;
  }
  __syncthreads();
  {
    u64 kk[8];
    #pragma unroll
    for (int w = 0; w < 8; w++) kk[w] = keepw[w];
    const int s = tid;
    const int wi = s >> 6, bi = s & 63;
    bool kept = (kk[wi] >> bi) & 1ull;
    if (kept){
      int rank = 0;
      for (int w = 0; w < wi; w++) rank += __popcll(kk[w]);
      rank += __popcll(bi ? (kk[wi] & ((1ull << bi) - 1ull)) : 0ull);
      if (rank < MAXDET){
        float4 ob = obs[s];
        float* sb = selbox + ((long)img*MAXDET + rank)*4;
        sb[0]=ob.x; sb[1]=ob.y; sb[2]=ob.z; sb[3]=ob.w;
      }
    }
    if (tid == 0){
      int tot = 0;
      #pragma unroll
      for (int w = 0; w < 8; w++) tot += __popcll(kk[w]);
      selcnt[img] = (u32)min(tot, MAXDET);
    }
  }
}

// ---------------- K5: projection GEMM, split-K balanced ----------------
// R8 theory: old full-K blocks had 8x duration spread (L4 32 stage rounds vs
// L1 4) -> 15.5% occupancy, heavy-block tail dominated the 115us. Now EVERY
// block = 128px x 64j x 128 channels (4 stage rounds of 32c): L4 8 K-splits,
// L3 4, L2 2, L1 1. Multi-split levels accumulate with fp32 atomicAdd into a
// zeroed G region (level-major layout so L2-L4 is one contiguous memset);
// L1 (75% of G) keeps plain float4 stores. Micro-tile 8px x 4j: 32 FMA per
// 3 ds_read_b128 (2x better FMA:LDS ratio than 4x4; LDS pipe was the
// projected secondary cap at ~12cyc/b128). Stage is reg-prefetch
// double-buffered (T14-lite) so global latency hides under the FMA loop.
// Fs reads keep the proven stride-16B / 4-way-broadcast pattern (0 conflicts).
__device__ __forceinline__ void load_chunk(const float4* __restrict__ feat4,
    const float4* __restrict__ W14, long fbase, int hw4, int px04, int Woff,
    int c0, int tid, float4 (&rF)[4], float4 (&rW)[2]){
  #pragma unroll
  for (int k = 0; k < 4; k++){
    int s = tid + k*256; int c = s >> 5, q = s & 31;
    int pq = px04 + q; if (pq >= hw4) pq = hw4 - 1;   // ragged tile clamp (stores guarded)
    rF[k] = feat4[fbase + (long)(c0 + c)*hw4 + pq];
  }
  #pragma unroll
  for (int k = 0; k < 2; k++){
    int s = tid + k*256; int c = s >> 4, q = s & 15;
    rW[k] = W14[(long)(Woff + c0 + c)*16 + q];
  }
}

#define FMA_ROW(S, A) \
  A.x = fmaf(S, wv.x, A.x); A.y = fmaf(S, wv.y, A.y); \
  A.z = fmaf(S, wv.z, A.z); A.w = fmaf(S, wv.w, A.w);

__global__ __launch_bounds__(256) void k_proj(const float* __restrict__ f1,
    const float* __restrict__ f2, const float* __restrict__ f3,
    const float* __restrict__ f4, const float* __restrict__ W1,
    float* __restrict__ G){
  __shared__ __align__(16) float Fs[32*128];   // 16 KB
  __shared__ __align__(16) float Ws[32*64];    // 8 KB
  const int img = blockIdx.y;
  const int u   = blockIdx.x;                  // 144 blocks/img, all equal work
  const float* feat; int C, HW, Woff, tile, split; long goff; bool multi;
  if (u < 16)      { feat=f4; C=1024; HW=144;  Woff=896; tile=u>>3;      split=u&7;      goff=G4_OFF; multi=true;  }
  else if (u < 36) { feat=f3; C=512;  HW=576;  Woff=384; tile=(u-16)>>2; split=(u-16)&3; goff=G3_OFF; multi=true;  }
  else if (u < 72) { feat=f2; C=256;  HW=2304; Woff=128; tile=(u-36)>>1; split=(u-36)&1; goff=G2_OFF; multi=true;  }
  else             { feat=f1; C=128;  HW=9216; Woff=0;   tile=u-72;      split=0;        goff=0;      multi=false; }
  const int px0  = tile*128;
  const int hw4  = HW >> 2;
  const int px04 = px0 >> 2;
  const int tid  = threadIdx.x;
  const int tx   = tid & 15;        // px group (8 px: quads tx and tx+16)
  const int ty   = tid >> 4;        // j group  (4 j)
  const int c0b  = split*128;
  const float4* feat4 = (const float4*)feat;
  const float4* W14   = (const float4*)W1;
  float4* Fs4 = (float4*)Fs;
  float4* Ws4 = (float4*)Ws;
  const long fbase = (long)img*C*hw4;
  float4 rF[4]; float4 rW[2];
  float4 a0 = make_float4(0.f,0.f,0.f,0.f), a1 = a0, a2 = a0, a3 = a0;
  float4 a4 = a0, a5 = a0, a6 = a0, a7 = a0;

  load_chunk(feat4, W14, fbase, hw4, px04, Woff, c0b, tid, rF, rW);
  for (int ch = 0; ch < 4; ch++){
    __syncthreads();                           // prev compute done -> LDS reusable
    #pragma unroll
    for (int k = 0; k < 4; k++) Fs4[tid + k*256] = rF[k];
    #pragma unroll
    for (int k = 0; k < 2; k++) Ws4[tid + k*256] = rW[k];
    if (ch < 3)                                // prefetch next chunk under compute
      load_chunk(feat4, W14, fbase, hw4, px04, Woff, c0b + (ch+1)*32, tid, rF, rW);
    __syncthreads();
    #pragma unroll 8
    for (int c = 0; c < 32; c++){
      float4 fa = Fs4[c*32 + tx];
      float4 fb = Fs4[c*32 + 16 + tx];
      float4 wv = Ws4[c*16 + ty];
      FMA_ROW(fa.x, a0) FMA_ROW(fa.y, a1) FMA_ROW(fa.z, a2) FMA_ROW(fa.w, a3)
      FMA_ROW(fb.x, a4) FMA_ROW(fb.y, a5) FMA_ROW(fb.z, a6) FMA_ROW(fb.w, a7)
    }
  }
  float* Gl = G + goff + (long)img*HW*64;
  const int pxa = px0 + tx*4;
#define STOREQ(A, GP) do { int gp = (GP); if (gp < HW){ \
    float* dst = Gl + (long)gp*64 + ty*4; \
    if (multi){ atomicAdd(dst, A.x); atomicAdd(dst+1, A.y); \
                atomicAdd(dst+2, A.z); atomicAdd(dst+3, A.w); } \
    else { *(float4*)dst = A; } } } while(0)
  STOREQ(a0, pxa + 0);  STOREQ(a1, pxa + 1);
  STOREQ(a2, pxa + 2);  STOREQ(a3, pxa + 3);
  STOREQ(a4, pxa + 64); STOREQ(a5, pxa + 65);
  STOREQ(a6, pxa + 66); STOREQ(a7, pxa + 67);
#undef STOREQ
}

// ---------------- K6: fused ROI-gather + bias + leaky + layer2 + assembly ----------------
__device__ __forceinline__ void roi_level(const float* __restrict__ g,
    int Hl, int Wl, float scale, float x1, float y1, float x2, float y2,
    int lane, float& h){
  float bx1=x1*scale, by1=y1*scale, bx2=x2*scale, by2=y2*scale;
  float rw=fmaxf(bx2-bx1,1.f), rh=fmaxf(by2-by1,1.f);
  float ys[2]={by1+rh*0.25f, by1+rh*0.75f};
  float xs[2]={bx1+rw*0.25f, bx1+rw*0.75f};
  #pragma unroll
  for (int pt = 0; pt < 4; pt++){
    float y=ys[pt>>1], x=xs[pt&1];
    if ((y>-1.f)&&(y<(float)Hl)&&(x>-1.f)&&(x<(float)Wl)){   // wave-uniform branch
      float yc=fmaxf(y,0.f), xc=fmaxf(x,0.f);
      int y0=(int)fminf(floorf(yc),(float)(Hl-1));
      int x0=(int)fminf(floorf(xc),(float)(Wl-1));
      int y1i=min(y0+1,Hl-1), x1i=min(x0+1,Wl-1);
      float ly=yc-(float)y0, lx=xc-(float)x0;
      float hy=1.f-ly, hx=1.f-lx;
      h += (hy*hx*0.25f)*g[(long)(y0*Wl+x0)*64+lane];
      h += (hy*lx*0.25f)*g[(long)(y0*Wl+x1i)*64+lane];
      h += (ly*hx*0.25f)*g[(long)(y1i*Wl+x0)*64+lane];
      h += (ly*lx*0.25f)*g[(long)(y1i*Wl+x1i)*64+lane];
    }
  }
}

__global__ __launch_bounds__(256) void k_roi_mlp(const float* __restrict__ G,
    const float* __restrict__ selbox, const u32* __restrict__ selcnt,
    const float* __restrict__ b1, const float* __restrict__ W2,
    const float* __restrict__ b2, float* __restrict__ out){
  const int img  = blockIdx.y;
  const int wave = threadIdx.x >> 6;
  const int lane = threadIdx.x & 63;
  const int slot = blockIdx.x*4 + wave;
  if (slot >= MAXDET) return;
  float* o = out + ((long)img*MAXDET + slot)*68;
  if (slot >= (int)selcnt[img]){
    o[4+lane] = 0.f;
    if (lane < 4) o[lane] = 0.f;
    return;
  }
  const float* sb = selbox + ((long)img*MAXDET + slot)*4;
  float x1 = sb[0], y1 = sb[1], x2 = sb[2], y2 = sb[3];
  const float* Gi1 = G +          (long)img*9216*64;
  const float* Gi2 = G + G2_OFF + (long)img*2304*64;
  const float* Gi3 = G + G3_OFF + (long)img*576*64;
  const float* Gi4 = G + G4_OFF + (long)img*144*64;
  float h = 0.f;
  roi_level(Gi1, 96, 96, 0.125f,    x1,y1,x2,y2, lane, h);
  roi_level(Gi2, 48, 48, 0.0625f,   x1,y1,x2,y2, lane, h);
  roi_level(Gi3, 24, 24, 0.03125f,  x1,y1,x2,y2, lane, h);
  roi_level(Gi4, 12, 12, 0.015625f, x1,y1,x2,y2, lane, h);
  float h1 = leaky(h + b1[lane]);
  float c = 0.f;
  #pragma unroll 8
  for (int k = 0; k < 64; k++){
    float hk = __shfl(h1, k, 64);
    c += hk * W2[k*64 + lane];
  }
  o[4+lane] = leaky(c + b2[lane]);
  if (lane < 4) o[lane] = sb[lane] / 768.0f;
}

// ---------------- workspace layout (bytes) ----------------
// 0        hist    u32[8][2048]        65536
// 65536    cnt     u32[8]              256 (padded)
// 65792    thr     u32[8]              256
// 66048    selbox  f32[8][300][4]      38400
// 104448   selcnt  u32[8]              256
// 104704   sbits   u32[8][36720]       1175040
// 1279744  cls     i32[8][36720]       1175040
// 2454784  cand    u64[8][1024]        65536
// 2520320  G       f32 level-major     25067520  -> total ~27.6 MB
//          L1 [8][9216][64] | L2 [8][2304][64] | L3 [8][576][64] | L4 [8][144][64]

extern "C" void kernel_launch(void* const* d_in, const int* in_sizes, int n_in,
                              void* d_out, int out_size, void* d_ws, size_t ws_size,
                              hipStream_t stream){
  const float* preds = (const float*)d_in[0];
  const float* f1 = (const float*)d_in[1];
  const float* f2 = (const float*)d_in[2];
  const float* f3 = (const float*)d_in[3];
  const float* f4 = (const float*)d_in[4];
  const float* W1 = (const float*)d_in[5];
  const float* b1 = (const float*)d_in[6];
  const float* W2 = (const float*)d_in[7];
  const float* b2 = (const float*)d_in[8];
  float* out = (float*)d_out;
  char* ws = (char*)d_ws;
  u32* hist   = (u32*)(ws + 0);
  u32* cnt    = (u32*)(ws + 65536);
  u32* thr    = (u32*)(ws + 65792);
  float* selb = (float*)(ws + 66048);
  u32* selc   = (u32*)(ws + 104448);
  u32* sbits  = (u32*)(ws + 104704);
  int* clsA   = (int*)(ws + 1279744);
  u64* cand   = (u64*)(ws + 2454784);
  float* G    = (float*)(ws + 2520320);

  hipMemsetAsync(ws, 0, 65792, stream);                       // hist + cnt
  hipMemsetAsync((char*)G + (size_t)G2_OFF*4, 0,
                 (size_t)(G_TOT - G2_OFF)*4, stream);         // L2-L4 atomic region

  dim3 gs((NCAND + 255)/256, B_IMG);
  k_score<<<gs, 256, 0, stream>>>(preds, sbits, clsA, hist);
  k_thresh<<<B_IMG, 64, 0, stream>>>(hist, thr);
  dim3 g3((NCAND+255)/256, B_IMG);
  k_gather<<<g3, 256, 0, stream>>>(sbits, thr, cnt, cand);
  k_nms<<<B_IMG, 512, 0, stream>>>(preds, clsA, cand, cnt, selb, selc);
  k_proj<<<dim3(144, B_IMG), 256, 0, stream>>>(f1, f2, f3, f4, W1, G);
  k_roi_mlp<<<dim3((MAXDET+3)/4, B_IMG), 256, 0, stream>>>(G, selb, selc, b1, W2, b2, out);
}

// Round 2
// 416.100 us; speedup vs baseline: 1.0840x; 1.0840x over previous
//
#include <hip/hip_runtime.h>
#include <cstdint>

#define B_IMG   8
#define NCAND   36720
#define PD      85
#define NCLS    80
#define KC      512
#define MAXDET  300
#define NBUCK   2048
#define CANDCAP 1024      // gathered count is ~512 + one-bucket (<~40): 1024 is safe

// G (fp32, level-major) float offsets: L1[8][9216][64] | L2[8][2304][64] | L3[8][576][64] | L4[8][144][64]
#define G2_OFF 4718592
#define G3_OFF 5898240
#define G4_OFF 6193152
#define G_TOT  6266880

// Partial-sum buffer P (float offsets within P):
//   P2: 2 slabs x (8*2304*64 = 1179648)
//   P3: 4 slabs x (8*576*64  = 294912)   base 2359296
//   P4: 8 slabs x (8*144*64  = 73728)    base 3538944
// total 4128768 floats = 16.5 MB
#define P2_BASE 0
#define P2_SLAB 1179648
#define P3_BASE 2359296
#define P3_SLAB 294912
#define P4_BASE 3538944
#define P4_SLAB 73728

typedef unsigned int u32;
typedef unsigned long long u64;

__device__ __forceinline__ float leaky(float x){ return x >= 0.f ? x : 0.01f*x; }

__device__ __forceinline__ u64 shfl_u64(u64 v, int lane){
  int lo = __shfl((int)(u32)(v & 0xFFFFFFFFull), lane, 64);
  int hi = __shfl((int)(u32)(v >> 32), lane, 64);
  return ((u64)(u32)hi << 32) | (u64)(u32)lo;
}
__device__ __forceinline__ u64 shfl_xor_u64(u64 v, int mask){
  int lo = __shfl_xor((int)(u32)(v & 0xFFFFFFFFull), mask, 64);
  int hi = __shfl_xor((int)(u32)(v >> 32), mask, 64);
  return ((u64)(u32)hi << 32) | (u64)(u32)lo;
}

// ---------------- K1: two-phase score: obj-filter -> class-scan survivors only ----
__global__ __launch_bounds__(256) void k_score(const float* __restrict__ preds,
    u32* __restrict__ sbits, int* __restrict__ clsArr, u32* __restrict__ hist){
  __shared__ u32   sl_lane[4][64];
  __shared__ float sl_obj[4][64];
  __shared__ u32   sl_res[4][64];
  __shared__ u32   sl_cls[4][64];
  const int img  = blockIdx.y;
  const int wv   = threadIdx.x >> 6;
  const int lane = threadIdx.x & 63;
  const int base = (blockIdx.x*4 + wv)*64;
  const int ci   = base + lane;
  const bool inb = ci < NCAND;
  float obj = 0.f;
  if (inb) obj = preds[((long)img*NCAND + ci)*PD + 4];
  const bool pass = obj > 0.596f;
  u64 mask = __ballot(pass);
  int cnt  = __popcll(mask);
  int rank = __popcll(mask & ((1ull << lane) - 1ull));
  if (pass){ sl_lane[wv][rank] = (u32)lane; sl_obj[wv][rank] = obj; }
  const int q = lane & 3;
  for (int r0 = 0; r0 < cnt; r0 += 16){
    int idx = r0 + (lane >> 2);
    if (idx < cnt){
      u32 sl = sl_lane[wv][idx];
      float obj2 = sl_obj[wv][idx];
      const float* p2 = preds + ((long)img*NCAND + base + (int)sl)*PD + 5 + q;
      u64 best = 0ull;
      #pragma unroll
      for (int k = 0; k < 20; k++){
        float v = p2[4*k] * obj2;                       // exact ref: cls*obj
        u64 key = ((u64)__float_as_uint(v) << 32) | (u64)(~(u32)(q + 4*k));
        if (key > best) best = key;                     // first max wins
      }
      u64 o1 = shfl_xor_u64(best, 1); if (o1 > best) best = o1;
      u64 o2 = shfl_xor_u64(best, 2); if (o2 > best) best = o2;
      if (q == 0){
        u32 bits = (u32)(best >> 32);
        sl_res[wv][sl] = (__uint_as_float(bits) > 0.596f) ? bits : 0u;
        sl_cls[wv][sl] = ~(u32)(best & 0xFFFFFFFFull);
      }
    }
  }
  if (inb){
    u32 out = pass ? sl_res[wv][lane] : 0u;             // valid scores in (0.596,1)
    sbits[(long)img*NCAND + ci] = out;
    if (pass) clsArr[(long)img*NCAND + ci] = (int)sl_cls[wv][lane];
    if (out) atomicAdd(&hist[img*NBUCK + ((out - 0x3F000000u) >> 12)], 1u);
  }
}

// ---------------- K2: per-image bit-threshold covering top-512 ----------------
__global__ __launch_bounds__(64) void k_thresh(const u32* __restrict__ hist,
                                               u32* __restrict__ thr){
  const int img = blockIdx.x;
  const int lane = threadIdx.x;
  const u32* h = hist + img*NBUCK;
  u32 acc = 0; u32 result = 0x3F000000u; bool found = false;
  for (int g = NBUCK/64 - 1; g >= 0 && !found; g--){
    u32 v = h[g*64 + lane];
    u32 s = v;
    #pragma unroll
    for (int off = 1; off < 64; off <<= 1){
      u32 t = __shfl_down(s, off, 64);
      s += (lane + off < 64) ? t : 0u;
    }
    u64 mask = __ballot(acc + s >= KC);
    if (mask){
      int hl = 63 - __clzll(mask);
      result = 0x3F000000u + ((u32)(g*64 + hl) << 12);
      found = true;
    }
    acc += __shfl(s, 0, 64);
  }
  if (lane == 0) thr[img] = result;
}

// ---------------- K3: gather candidates >= threshold as sortable keys ----------------
__global__ __launch_bounds__(256) void k_gather(const u32* __restrict__ sbits,
    const u32* __restrict__ thr, u32* __restrict__ cnt, u64* __restrict__ cand){
  int img = blockIdx.y;
  int n = blockIdx.x*256 + threadIdx.x;
  if (n >= NCAND) return;
  u32 bits = sbits[(long)img*NCAND + n];
  if (bits && bits >= thr[img]){
    u32 pos = atomicAdd(&cnt[img], 1u);
    if (pos < CANDCAP)
      cand[(long)img*CANDCAP + pos] = ((u64)bits << 32) | (u64)(0xFFFFFFFFu - (u32)n);
  }
}

// ---------------- K4: fused NMS: rank -> decode -> IOU matrix -> greedy -> compact ----
__global__ __launch_bounds__(512) void k_nms(const float* __restrict__ preds,
    const int* __restrict__ clsArr, const u64* __restrict__ cand,
    const u32* __restrict__ cnt, float* __restrict__ selbox, u32* __restrict__ selcnt){
#pragma clang fp contract(off)
  __shared__ __align__(16) u64 keys[CANDCAP];      // 8 KB
  __shared__ float4 cbs[KC];                       // 8 KB  class-offset boxes
  __shared__ float4 obs[KC];                       // 8 KB  original boxes
  __shared__ u64 lrows[KC*8];                      // 32 KB suppression matrix
  __shared__ u64 kmask[8];
  __shared__ u64 keepw[8];
  const int img = blockIdx.x;
  const int tid = threadIdx.x;
  const int M = min((int)cnt[img], CANDCAP);
  keys[tid]       = (tid < M)       ? cand[(long)img*CANDCAP + tid]       : 0ull;
  keys[tid + 512] = (tid + 512 < M) ? cand[(long)img*CANDCAP + tid + 512] : 0ull;
  cbs[tid] = make_float4(-4e8f, -4e8f, -4e8f, -4e8f);   // zero-area -> iou 0
  obs[tid] = make_float4(0.f, 0.f, 0.f, 0.f);
  if (tid < 8) kmask[tid] = 0ull;
  __syncthreads();
  // ---- rank by count (desc): rank = #{keys strictly greater} ----
  u64 k0 = keys[tid], k1 = keys[tid + 512];
  int r0 = 0, r1 = 0;
  const ulonglong2* kv = (const ulonglong2*)keys;
  for (int j = 0; j < CANDCAP/2; j++){              // wave-uniform b128 broadcast
    ulonglong2 kk = kv[j];
    r0 += (kk.x > k0) + (kk.y > k0);
    r1 += (kk.x > k1) + (kk.y > k1);
  }
  #pragma unroll
  for (int t = 0; t < 2; t++){
    u64 key = t ? k1 : k0;
    int rank = t ? r1 : r0;
    if ((key >> 32) != 0ull && rank < KC){
      u32 idxn = 0xFFFFFFFFu - (u32)(key & 0xFFFFFFFFull);
      const float* p = preds + ((long)img*NCAND + idxn)*PD;
      float cx = p[0], cy = p[1], w = p[2], h = p[3];
      float hw = w*0.5f, hh = h*0.5f;               // exact
      float X1 = cx-hw, Y1 = cy-hh, X2 = cx+hw, Y2 = cy+hh;
      float off = (float)clsArr[(long)img*NCAND + idxn] * 4096.0f;  // exact
      obs[rank] = make_float4(X1, Y1, X2, Y2);
      cbs[rank] = make_float4(X1+off, Y1+off, X2+off, Y2+off);
      atomicOr(&kmask[rank >> 6], 1ull << (rank & 63));
    }
  }
  __syncthreads();
  {
    const int i = tid;
    float4 bi = cbs[i];
    float areai = (bi.z - bi.x)*(bi.w - bi.y);
    for (int w = 0; w < 8; w++){
      u64 bits = 0ull;
      int jbase = w*64;
      for (int b = 0; b < 64; b++){
        int j = jbase + b;
        if (j > i){
          float4 bj = cbs[j];
          float areaj = (bj.z - bj.x)*(bj.w - bj.y);
          float ltx = fmaxf(bi.x, bj.x), lty = fmaxf(bi.y, bj.y);
          float rbx = fminf(bi.z, bj.z), rby = fminf(bi.w, bj.w);
          float ww = fmaxf(rbx - ltx, 0.f);
          float hh = fmaxf(rby - lty, 0.f);
          float inter = ww*hh;
          float iou = inter / (areai + areaj - inter + 1e-7f);  // exact ref op order
          if (iou > 0.45f) bits |= (1ull << b);
        }
      }
      lrows[i*8 + w] = bits;
    }
  }
  __syncthreads();
  // ---- greedy: wave 0, lane-local blocked update ----
  if (tid < 64){
    const int lane = tid;
    const int w = lane & 7;
    u64 kw_own = kmask[w];
    for (int b = 0; b < 8; b++){
      u64 kwb = shfl_u64(kw_own, b);
      for (int g = 0; g < 8; g++){
        u64 rdec[8], rown[8];
        #pragma unroll
        for (int k = 0; k < 8; k++){
          int i = b*64 + g*8 + k;
          rdec[k] = lrows[i*8 + b];
          rown[k] = lrows[i*8 + w];
        }
        #pragma unroll
        for (int k = 0; k < 8; k++){
          int il = g*8 + k;
          if ((kwb >> il) & 1ull){
            kwb    &= ~rdec[k];
            kw_own &= ~rown[k];
          }
        }
      }
    }
    if (lane < 8) keepw[lane] = kw_own;
  }
  __syncthreads();
  {
    u64 kk[8];
    #pragma unroll
    for (int w = 0; w < 8; w++) kk[w] = keepw[w];
    const int s = tid;
    const int wi = s >> 6, bi = s & 63;
    bool kept = (kk[wi] >> bi) & 1ull;
    if (kept){
      int rank = 0;
      for (int w = 0; w < wi; w++) rank += __popcll(kk[w]);
      rank += __popcll(bi ? (kk[wi] & ((1ull << bi) - 1ull)) : 0ull);
      if (rank < MAXDET){
        float4 ob = obs[s];
        float* sb = selbox + ((long)img*MAXDET + rank)*4;
        sb[0]=ob.x; sb[1]=ob.y; sb[2]=ob.z; sb[3]=ob.w;
      }
    }
    if (tid == 0){
      int tot = 0;
      #pragma unroll
      for (int w = 0; w < 8; w++) tot += __popcll(kk[w]);
      selcnt[img] = (u32)min(tot, MAXDET);
    }
  }
}

// ---------------- K5: projection GEMM, split-K balanced, NO atomics ----------------
// R9: R8's atomicAdd accumulation caused 8x write amplification (WRITE_SIZE
// 180MB vs ~22MB useful; scalar device-scope atomics = one EA transaction
// each, no L2 merge) -> k_proj stayed 119us despite balanced blocks. Now each
// K-split writes its own partial slab with plain coalesced float4 stores; a
// tiny k_reduce sums slabs (fixed channel order -> deterministic). L1 (75% of
// G) is single-split and still writes G directly. No G memset needed.
__device__ __forceinline__ void load_chunk(const float4* __restrict__ feat4,
    const float4* __restrict__ W14, long fbase, int hw4, int px04, int Woff,
    int c0, int tid, float4 (&rF)[4], float4 (&rW)[2]){
  #pragma unroll
  for (int k = 0; k < 4; k++){
    int s = tid + k*256; int c = s >> 5, q = s & 31;
    int pq = px04 + q; if (pq >= hw4) pq = hw4 - 1;   // ragged tile clamp (stores guarded)
    rF[k] = feat4[fbase + (long)(c0 + c)*hw4 + pq];
  }
  #pragma unroll
  for (int k = 0; k < 2; k++){
    int s = tid + k*256; int c = s >> 4, q = s & 15;
    rW[k] = W14[(long)(Woff + c0 + c)*16 + q];
  }
}

#define FMA_ROW(S, A) \
  A.x = fmaf(S, wv.x, A.x); A.y = fmaf(S, wv.y, A.y); \
  A.z = fmaf(S, wv.z, A.z); A.w = fmaf(S, wv.w, A.w);

__global__ __launch_bounds__(256) void k_proj(const float* __restrict__ f1,
    const float* __restrict__ f2, const float* __restrict__ f3,
    const float* __restrict__ f4, const float* __restrict__ W1,
    float* __restrict__ G, float* __restrict__ P){
  __shared__ __align__(16) float Fs[32*128];   // 16 KB
  __shared__ __align__(16) float Ws[32*64];    // 8 KB
  const int img = blockIdx.y;
  const int u   = blockIdx.x;                  // 144 blocks/img, all equal work
  const float* feat; int C, HW, Woff, tile, split; long pbase; bool multi;
  if (u < 16)      { feat=f4; C=1024; HW=144;  Woff=896; tile=u>>3;      split=u&7;
                     pbase=P4_BASE + (long)split*P4_SLAB; multi=true;  }
  else if (u < 36) { feat=f3; C=512;  HW=576;  Woff=384; tile=(u-16)>>2; split=(u-16)&3;
                     pbase=P3_BASE + (long)split*P3_SLAB; multi=true;  }
  else if (u < 72) { feat=f2; C=256;  HW=2304; Woff=128; tile=(u-36)>>1; split=(u-36)&1;
                     pbase=P2_BASE + (long)split*P2_SLAB; multi=true;  }
  else             { feat=f1; C=128;  HW=9216; Woff=0;   tile=u-72;      split=0;
                     pbase=0; multi=false; }
  const int px0  = tile*128;
  const int hw4  = HW >> 2;
  const int px04 = px0 >> 2;
  const int tid  = threadIdx.x;
  const int tx   = tid & 15;        // px group (8 px: quads tx and tx+16)
  const int ty   = tid >> 4;        // j group  (4 j)
  const int c0b  = split*128;
  const float4* feat4 = (const float4*)feat;
  const float4* W14   = (const float4*)W1;
  float4* Fs4 = (float4*)Fs;
  float4* Ws4 = (float4*)Ws;
  const long fbase = (long)img*C*hw4;
  float4 rF[4]; float4 rW[2];
  float4 a0 = make_float4(0.f,0.f,0.f,0.f), a1 = a0, a2 = a0, a3 = a0;
  float4 a4 = a0, a5 = a0, a6 = a0, a7 = a0;

  load_chunk(feat4, W14, fbase, hw4, px04, Woff, c0b, tid, rF, rW);
  for (int ch = 0; ch < 4; ch++){
    __syncthreads();                           // prev compute done -> LDS reusable
    #pragma unroll
    for (int k = 0; k < 4; k++) Fs4[tid + k*256] = rF[k];
    #pragma unroll
    for (int k = 0; k < 2; k++) Ws4[tid + k*256] = rW[k];
    if (ch < 3)                                // prefetch next chunk under compute
      load_chunk(feat4, W14, fbase, hw4, px04, Woff, c0b + (ch+1)*32, tid, rF, rW);
    __syncthreads();
    #pragma unroll 8
    for (int c = 0; c < 32; c++){
      float4 fa = Fs4[c*32 + tx];
      float4 fb = Fs4[c*32 + 16 + tx];
      float4 wv = Ws4[c*16 + ty];
      FMA_ROW(fa.x, a0) FMA_ROW(fa.y, a1) FMA_ROW(fa.z, a2) FMA_ROW(fa.w, a3)
      FMA_ROW(fb.x, a4) FMA_ROW(fb.y, a5) FMA_ROW(fb.z, a6) FMA_ROW(fb.w, a7)
    }
  }
  float* outb = multi ? (P + pbase + (long)img*HW*64)
                      : (G + (long)img*HW*64);           // L1 region starts at G+0
  const int pxa = px0 + tx*4;
#define STOREQ(A, GP) do { int gp = (GP); if (gp < HW){ \
    *(float4*)(outb + (long)gp*64 + ty*4) = A; } } while(0)
  STOREQ(a0, pxa + 0);  STOREQ(a1, pxa + 1);
  STOREQ(a2, pxa + 2);  STOREQ(a3, pxa + 3);
  STOREQ(a4, pxa + 64); STOREQ(a5, pxa + 65);
  STOREQ(a6, pxa + 66); STOREQ(a7, pxa + 67);
#undef STOREQ
}

// ---------------- K5b: sum split-K partial slabs into final G (L2-L4 region) ----
// One float4 per thread, fully coalesced; split order ascending = channel order.
__global__ __launch_bounds__(256) void k_reduce(const float4* __restrict__ P4f,
                                                float4* __restrict__ G4f){
  const int N2 = P2_SLAB/4;   // 294912 f4
  const int N3 = P3_SLAB/4;   // 73728  f4
  const int N4 = P4_SLAB/4;   // 18432  f4
  int t = blockIdx.x*256 + threadIdx.x;
  if (t < N2){
    float4 a = P4f[t];
    float4 b = P4f[N2 + t];
    float4 r = make_float4(a.x+b.x, a.y+b.y, a.z+b.z, a.w+b.w);
    G4f[G2_OFF/4 + t] = r;
  } else if (t < N2 + N3){
    int u = t - N2;
    const float4* base = P4f + P3_BASE/4 + u;
    float4 r = base[0];
    #pragma unroll
    for (int s = 1; s < 4; s++){
      float4 b = base[(long)s*N3];
      r.x += b.x; r.y += b.y; r.z += b.z; r.w += b.w;
    }
    G4f[G3_OFF/4 + u] = r;
  } else if (t < N2 + N3 + N4){
    int u = t - N2 - N3;
    const float4* base = P4f + P4_BASE/4 + u;
    float4 r = base[0];
    #pragma unroll
    for (int s = 1; s < 8; s++){
      float4 b = base[(long)s*N4];
      r.x += b.x; r.y += b.y; r.z += b.z; r.w += b.w;
    }
    G4f[G4_OFF/4 + u] = r;
  }
}

// ---------------- K6: fused ROI-gather + bias + leaky + layer2 + assembly ----------------
__device__ __forceinline__ void roi_level(const float* __restrict__ g,
    int Hl, int Wl, float scale, float x1, float y1, float x2, float y2,
    int lane, float& h){
  float bx1=x1*scale, by1=y1*scale, bx2=x2*scale, by2=y2*scale;
  float rw=fmaxf(bx2-bx1,1.f), rh=fmaxf(by2-by1,1.f);
  float ys[2]={by1+rh*0.25f, by1+rh*0.75f};
  float xs[2]={bx1+rw*0.25f, bx1+rw*0.75f};
  #pragma unroll
  for (int pt = 0; pt < 4; pt++){
    float y=ys[pt>>1], x=xs[pt&1];
    if ((y>-1.f)&&(y<(float)Hl)&&(x>-1.f)&&(x<(float)Wl)){   // wave-uniform branch
      float yc=fmaxf(y,0.f), xc=fmaxf(x,0.f);
      int y0=(int)fminf(floorf(yc),(float)(Hl-1));
      int x0=(int)fminf(floorf(xc),(float)(Wl-1));
      int y1i=min(y0+1,Hl-1), x1i=min(x0+1,Wl-1);
      float ly=yc-(float)y0, lx=xc-(float)x0;
      float hy=1.f-ly, hx=1.f-lx;
      h += (hy*hx*0.25f)*g[(long)(y0*Wl+x0)*64+lane];
      h += (hy*lx*0.25f)*g[(long)(y0*Wl+x1i)*64+lane];
      h += (ly*hx*0.25f)*g[(long)(y1i*Wl+x0)*64+lane];
      h += (ly*lx*0.25f)*g[(long)(y1i*Wl+x1i)*64+lane];
    }
  }
}

__global__ __launch_bounds__(256) void k_roi_mlp(const float* __restrict__ G,
    const float* __restrict__ selbox, const u32* __restrict__ selcnt,
    const float* __restrict__ b1, const float* __restrict__ W2,
    const float* __restrict__ b2, float* __restrict__ out){
  const int img  = blockIdx.y;
  const int wave = threadIdx.x >> 6;
  const int lane = threadIdx.x & 63;
  const int slot = blockIdx.x*4 + wave;
  if (slot >= MAXDET) return;
  float* o = out + ((long)img*MAXDET + slot)*68;
  if (slot >= (int)selcnt[img]){
    o[4+lane] = 0.f;
    if (lane < 4) o[lane] = 0.f;
    return;
  }
  const float* sb = selbox + ((long)img*MAXDET + slot)*4;
  float x1 = sb[0], y1 = sb[1], x2 = sb[2], y2 = sb[3];
  const float* Gi1 = G +          (long)img*9216*64;
  const float* Gi2 = G + G2_OFF + (long)img*2304*64;
  const float* Gi3 = G + G3_OFF + (long)img*576*64;
  const float* Gi4 = G + G4_OFF + (long)img*144*64;
  float h = 0.f;
  roi_level(Gi1, 96, 96, 0.125f,    x1,y1,x2,y2, lane, h);
  roi_level(Gi2, 48, 48, 0.0625f,   x1,y1,x2,y2, lane, h);
  roi_level(Gi3, 24, 24, 0.03125f,  x1,y1,x2,y2, lane, h);
  roi_level(Gi4, 12, 12, 0.015625f, x1,y1,x2,y2, lane, h);
  float h1 = leaky(h + b1[lane]);
  float c = 0.f;
  #pragma unroll 8
  for (int k = 0; k < 64; k++){
    float hk = __shfl(h1, k, 64);
    c += hk * W2[k*64 + lane];
  }
  o[4+lane] = leaky(c + b2[lane]);
  if (lane < 4) o[lane] = sb[lane] / 768.0f;
}

// ---------------- workspace layout (bytes) ----------------
// 0        hist    u32[8][2048]        65536
// 65536    cnt     u32[8]              256 (padded)
// 65792    thr     u32[8]              256
// 66048    selbox  f32[8][300][4]      38400
// 104448   selcnt  u32[8]              256
// 104704   sbits   u32[8][36720]       1175040
// 1279744  cls     i32[8][36720]       1175040
// 2454784  cand    u64[8][1024]        65536
// 2520320  G       f32 level-major     25067520
// 27587840 P       f32 partials        16515072   -> total ~44.1 MB
#define WS_G 2520320
#define WS_P 27587840

extern "C" void kernel_launch(void* const* d_in, const int* in_sizes, int n_in,
                              void* d_out, int out_size, void* d_ws, size_t ws_size,
                              hipStream_t stream){
  const float* preds = (const float*)d_in[0];
  const float* f1 = (const float*)d_in[1];
  const float* f2 = (const float*)d_in[2];
  const float* f3 = (const float*)d_in[3];
  const float* f4 = (const float*)d_in[4];
  const float* W1 = (const float*)d_in[5];
  const float* b1 = (const float*)d_in[6];
  const float* W2 = (const float*)d_in[7];
  const float* b2 = (const float*)d_in[8];
  float* out = (float*)d_out;
  char* ws = (char*)d_ws;
  u32* hist   = (u32*)(ws + 0);
  u32* cnt    = (u32*)(ws + 65536);
  u32* thr    = (u32*)(ws + 65792);
  float* selb = (float*)(ws + 66048);
  u32* selc   = (u32*)(ws + 104448);
  u32* sbits  = (u32*)(ws + 104704);
  int* clsA   = (int*)(ws + 1279744);
  u64* cand   = (u64*)(ws + 2454784);
  float* G    = (float*)(ws + WS_G);
  float* P    = (float*)(ws + WS_P);

  hipMemsetAsync(ws, 0, 65792, stream);                       // hist + cnt only

  dim3 gs((NCAND + 255)/256, B_IMG);
  k_score<<<gs, 256, 0, stream>>>(preds, sbits, clsA, hist);
  k_thresh<<<B_IMG, 64, 0, stream>>>(hist, thr);
  dim3 g3((NCAND+255)/256, B_IMG);
  k_gather<<<g3, 256, 0, stream>>>(sbits, thr, cnt, cand);
  k_nms<<<B_IMG, 512, 0, stream>>>(preds, clsA, cand, cnt, selb, selc);
  k_proj<<<dim3(144, B_IMG), 256, 0, stream>>>(f1, f2, f3, f4, W1, G, P);
  // reduce L2-L4 partial slabs into final G: (294912+73728+18432) f4 / 256
  k_reduce<<<1512, 256, 0, stream>>>((const float4*)P, (float4*)G);
  k_roi_mlp<<<dim3((MAXDET+3)/4, B_IMG), 256, 0, stream>>>(G, selb, selc, b1, W2, b2, out);
}

// Round 3
// 359.424 us; speedup vs baseline: 1.2549x; 1.1577x over previous
//
#include <hip/hip_runtime.h>
#include <cstdint>

#define B_IMG   8
#define NCAND   36720
#define PD      85
#define NCLS    80
#define KC      512
#define MAXDET  300
#define NBUCK   2048
#define CANDCAP 1024      // gathered count is ~512 + one-bucket (<~40): 1024 is safe

// G (fp32, level-major) float offsets: L1[8][9216][64] | L2[8][2304][64] | L3[8][576][64] | L4[8][144][64]
#define G2_OFF 4718592
#define G3_OFF 5898240
#define G4_OFF 6193152
#define G_TOT  6266880

// Partial-sum buffer P (float offsets within P)
#define P2_BASE 0
#define P2_SLAB 1179648
#define P3_BASE 2359296
#define P3_SLAB 294912
#define P4_BASE 3538944
#define P4_SLAB 73728

typedef unsigned int u32;
typedef unsigned long long u64;

__device__ __forceinline__ float leaky(float x){ return x >= 0.f ? x : 0.01f*x; }

__device__ __forceinline__ u64 shfl_u64(u64 v, int lane){
  int lo = __shfl((int)(u32)(v & 0xFFFFFFFFull), lane, 64);
  int hi = __shfl((int)(u32)(v >> 32), lane, 64);
  return ((u64)(u32)hi << 32) | (u64)(u32)lo;
}
__device__ __forceinline__ u64 shfl_xor_u64(u64 v, int mask){
  int lo = __shfl_xor((int)(u32)(v & 0xFFFFFFFFull), mask, 64);
  int hi = __shfl_xor((int)(u32)(v >> 32), mask, 64);
  return ((u64)(u32)hi << 32) | (u64)(u32)lo;
}

// ---------------- K1: two-phase score: obj-filter -> class-scan survivors only ----
__global__ __launch_bounds__(256) void k_score(const float* __restrict__ preds,
    u32* __restrict__ sbits, int* __restrict__ clsArr, u32* __restrict__ hist){
  __shared__ u32   sl_lane[4][64];
  __shared__ float sl_obj[4][64];
  __shared__ u32   sl_res[4][64];
  __shared__ u32   sl_cls[4][64];
  const int img  = blockIdx.y;
  const int wv   = threadIdx.x >> 6;
  const int lane = threadIdx.x & 63;
  const int base = (blockIdx.x*4 + wv)*64;
  const int ci   = base + lane;
  const bool inb = ci < NCAND;
  float obj = 0.f;
  if (inb) obj = preds[((long)img*NCAND + ci)*PD + 4];
  const bool pass = obj > 0.596f;
  u64 mask = __ballot(pass);
  int cnt  = __popcll(mask);
  int rank = __popcll(mask & ((1ull << lane) - 1ull));
  if (pass){ sl_lane[wv][rank] = (u32)lane; sl_obj[wv][rank] = obj; }
  const int q = lane & 3;
  for (int r0 = 0; r0 < cnt; r0 += 16){
    int idx = r0 + (lane >> 2);
    if (idx < cnt){
      u32 sl = sl_lane[wv][idx];
      float obj2 = sl_obj[wv][idx];
      const float* p2 = preds + ((long)img*NCAND + base + (int)sl)*PD + 5 + q;
      u64 best = 0ull;
      #pragma unroll
      for (int k = 0; k < 20; k++){
        float v = p2[4*k] * obj2;                       // exact ref: cls*obj
        u64 key = ((u64)__float_as_uint(v) << 32) | (u64)(~(u32)(q + 4*k));
        if (key > best) best = key;                     // first max wins
      }
      u64 o1 = shfl_xor_u64(best, 1); if (o1 > best) best = o1;
      u64 o2 = shfl_xor_u64(best, 2); if (o2 > best) best = o2;
      if (q == 0){
        u32 bits = (u32)(best >> 32);
        sl_res[wv][sl] = (__uint_as_float(bits) > 0.596f) ? bits : 0u;
        sl_cls[wv][sl] = ~(u32)(best & 0xFFFFFFFFull);
      }
    }
  }
  if (inb){
    u32 out = pass ? sl_res[wv][lane] : 0u;             // valid scores in (0.596,1)
    sbits[(long)img*NCAND + ci] = out;
    if (pass) clsArr[(long)img*NCAND + ci] = (int)sl_cls[wv][lane];
    if (out) atomicAdd(&hist[img*NBUCK + ((out - 0x3F000000u) >> 12)], 1u);
  }
}

// ---------------- K2: per-image bit-threshold covering top-512 ----------------
__global__ __launch_bounds__(64) void k_thresh(const u32* __restrict__ hist,
                                               u32* __restrict__ thr){
  const int img = blockIdx.x;
  const int lane = threadIdx.x;
  const u32* h = hist + img*NBUCK;
  u32 acc = 0; u32 result = 0x3F000000u; bool found = false;
  for (int g = NBUCK/64 - 1; g >= 0 && !found; g--){
    u32 v = h[g*64 + lane];
    u32 s = v;
    #pragma unroll
    for (int off = 1; off < 64; off <<= 1){
      u32 t = __shfl_down(s, off, 64);
      s += (lane + off < 64) ? t : 0u;
    }
    u64 mask = __ballot(acc + s >= KC);
    if (mask){
      int hl = 63 - __clzll(mask);
      result = 0x3F000000u + ((u32)(g*64 + hl) << 12);
      found = true;
    }
    acc += __shfl(s, 0, 64);
  }
  if (lane == 0) thr[img] = result;
}

// ---------------- K3: gather candidates >= threshold as sortable keys ----------------
__global__ __launch_bounds__(256) void k_gather(const u32* __restrict__ sbits,
    const u32* __restrict__ thr, u32* __restrict__ cnt, u64* __restrict__ cand){
  int img = blockIdx.y;
  int n = blockIdx.x*256 + threadIdx.x;
  if (n >= NCAND) return;
  u32 bits = sbits[(long)img*NCAND + n];
  if (bits && bits >= thr[img]){
    u32 pos = atomicAdd(&cnt[img], 1u);
    if (pos < CANDCAP)
      cand[(long)img*CANDCAP + pos] = ((u64)bits << 32) | (u64)(0xFFFFFFFFu - (u32)n);
  }
}

// ---------------- K4a: rank + decode ranked boxes to global ----------------
// R10: old fused k_nms ran 8 blocks (0.72% occupancy) for 122us. Split into
// rank (32 blocks) / iou (64 blocks) / greedy (8 blocks, serial part only).
// Identical arithmetic, relocated; result bit-identical.
__global__ __launch_bounds__(256) void k_rank(const float* __restrict__ preds,
    const int* __restrict__ clsArr, const u64* __restrict__ cand,
    const u32* __restrict__ cnt, float4* __restrict__ cbs_g,
    float4* __restrict__ obs_g, u64* __restrict__ kmask_g){
#pragma clang fp contract(off)
  __shared__ __align__(16) u64 keys[CANDCAP];      // 8 KB
  const int img = blockIdx.x >> 2;
  const int sub = blockIdx.x & 3;
  const int tid = threadIdx.x;
  const int M = min((int)cnt[img], CANDCAP);
  #pragma unroll
  for (int k = 0; k < 4; k++){
    int s = k*256 + tid;
    keys[s] = (s < M) ? cand[(long)img*CANDCAP + s] : 0ull;
  }
  __syncthreads();
  const int slot = sub*256 + tid;
  u64 k0 = keys[slot];
  int r0 = 0;
  const ulonglong2* kv = (const ulonglong2*)keys;
  for (int j = 0; j < CANDCAP/2; j++){              // wave-uniform b128 broadcast
    ulonglong2 kk = kv[j];
    r0 += (kk.x > k0) + (kk.y > k0);
  }
  if ((k0 >> 32) != 0ull && r0 < KC){
    u32 idxn = 0xFFFFFFFFu - (u32)(k0 & 0xFFFFFFFFull);
    const float* p = preds + ((long)img*NCAND + idxn)*PD;
    float cx = p[0], cy = p[1], w = p[2], h = p[3];
    float hw = w*0.5f, hh = h*0.5f;                 // exact
    float X1 = cx-hw, Y1 = cy-hh, X2 = cx+hw, Y2 = cy+hh;
    float off = (float)clsArr[(long)img*NCAND + idxn] * 4096.0f;  // exact
    obs_g[(long)img*KC + r0] = make_float4(X1, Y1, X2, Y2);
    cbs_g[(long)img*KC + r0] = make_float4(X1+off, Y1+off, X2+off, Y2+off);
    atomicOr(&kmask_g[img*8 + (r0 >> 6)], 1ull << (r0 & 63));
  }
}

// ---------------- K4b: IOU suppression matrix, 64 rows x 512 cols per block ----
__global__ __launch_bounds__(512) void k_iou(const float4* __restrict__ cbs_g,
    const u64* __restrict__ kmask_g, u64* __restrict__ lrows_g){
#pragma clang fp contract(off)
  __shared__ __align__(16) float4 cbsL[8*65];      // stride-65 swizzle: conflict-free
  const int img = blockIdx.x >> 3;
  const int ch  = blockIdx.x & 7;
  const int tid = threadIdx.x;
  if (tid < KC){
    u64 km = kmask_g[img*8 + (tid >> 6)];
    bool f = (km >> (tid & 63)) & 1ull;
    float4 v = f ? cbs_g[(long)img*KC + tid]
                 : make_float4(-4e8f, -4e8f, -4e8f, -4e8f);  // zero-area -> iou 0
    cbsL[(tid >> 6)*65 + (tid & 63)] = v;
  }
  __syncthreads();
  const int row = ch*64 + (tid >> 3);
  const int w   = tid & 7;
  float4 bi = cbsL[(row >> 6)*65 + (row & 63)];
  float areai = (bi.z - bi.x)*(bi.w - bi.y);
  u64 bits = 0ull;
  const int jbase = w*64;
  for (int b = 0; b < 64; b++){
    int j = jbase + b;
    if (j > row){
      float4 bj = cbsL[w*65 + b];
      float areaj = (bj.z - bj.x)*(bj.w - bj.y);
      float ltx = fmaxf(bi.x, bj.x), lty = fmaxf(bi.y, bj.y);
      float rbx = fminf(bi.z, bj.z), rby = fminf(bi.w, bj.w);
      float ww = fmaxf(rbx - ltx, 0.f);
      float hh = fmaxf(rby - lty, 0.f);
      float inter = ww*hh;
      float iou = inter / (areai + areaj - inter + 1e-7f);  // exact ref op order
      if (iou > 0.45f) bits |= (1ull << b);
    }
  }
  lrows_g[((long)img*KC + row)*8 + w] = bits;      // coalesced 8B stores
}

// ---------------- K4c: greedy suppression (serial core) + compact ----------------
__global__ __launch_bounds__(512) void k_greedy(const u64* __restrict__ lrows_g,
    const u64* __restrict__ kmask_g, const float4* __restrict__ obs_g,
    float* __restrict__ selbox, u32* __restrict__ selcnt){
  __shared__ __align__(16) u64 lrows[KC*8];        // 32 KB
  __shared__ u64 keepw[8];
  const int img = blockIdx.x;
  const int tid = threadIdx.x;
  const ulonglong2* src = (const ulonglong2*)(lrows_g + (long)img*KC*8);
  ulonglong2* dst = (ulonglong2*)lrows;
  #pragma unroll
  for (int k = 0; k < 4; k++) dst[k*512 + tid] = src[k*512 + tid];
  __syncthreads();
  if (tid < 64){
    const int lane = tid;
    const int w = lane & 7;
    u64 kw_own = kmask_g[img*8 + w];
    for (int b = 0; b < 8; b++){
      u64 kwb = shfl_u64(kw_own, b);
      for (int g = 0; g < 8; g++){
        u64 rdec[8], rown[8];
        #pragma unroll
        for (int k = 0; k < 8; k++){
          int i = b*64 + g*8 + k;
          rdec[k] = lrows[i*8 + b];
          rown[k] = lrows[i*8 + w];
        }
        #pragma unroll
        for (int k = 0; k < 8; k++){
          int il = g*8 + k;
          if ((kwb >> il) & 1ull){
            kwb    &= ~rdec[k];
            kw_own &= ~rown[k];
          }
        }
      }
    }
    if (lane < 8) keepw[lane] = kw_own;
  }
  __syncthreads();
  {
    u64 kk[8];
    #pragma unroll
    for (int w = 0; w < 8; w++) kk[w] = keepw[w];
    const int s = tid;
    const int wi = s >> 6, bi = s & 63;
    bool kept = (kk[wi] >> bi) & 1ull;
    if (kept){
      int rank = 0;
      for (int w = 0; w < wi; w++) rank += __popcll(kk[w]);
      rank += __popcll(bi ? (kk[wi] & ((1ull << bi) - 1ull)) : 0ull);
      if (rank < MAXDET){
        float4 ob = obs_g[(long)img*KC + s];
        float* sb = selbox + ((long)img*MAXDET + rank)*4;
        sb[0]=ob.x; sb[1]=ob.y; sb[2]=ob.z; sb[3]=ob.w;
      }
    }
    if (tid == 0){
      int tot = 0;
      #pragma unroll
      for (int w = 0; w < 8; w++) tot += __popcll(kk[w]);
      selcnt[img] = (u32)min(tot, MAXDET);
    }
  }
}

// ---------------- K5: projection GEMM, split-K balanced, NO atomics ----------------
__device__ __forceinline__ void load_chunk(const float4* __restrict__ feat4,
    const float4* __restrict__ W14, long fbase, int hw4, int px04, int Woff,
    int c0, int tid, float4 (&rF)[4], float4 (&rW)[2]){
  #pragma unroll
  for (int k = 0; k < 4; k++){
    int s = tid + k*256; int c = s >> 5, q = s & 31;
    int pq = px04 + q; if (pq >= hw4) pq = hw4 - 1;   // ragged tile clamp (stores guarded)
    rF[k] = feat4[fbase + (long)(c0 + c)*hw4 + pq];
  }
  #pragma unroll
  for (int k = 0; k < 2; k++){
    int s = tid + k*256; int c = s >> 4, q = s & 15;
    rW[k] = W14[(long)(Woff + c0 + c)*16 + q];
  }
}

#define FMA_ROW(S, A) \
  A.x = fmaf(S, wv.x, A.x); A.y = fmaf(S, wv.y, A.y); \
  A.z = fmaf(S, wv.z, A.z); A.w = fmaf(S, wv.w, A.w);

__global__ __launch_bounds__(256) void k_proj(const float* __restrict__ f1,
    const float* __restrict__ f2, const float* __restrict__ f3,
    const float* __restrict__ f4, const float* __restrict__ W1,
    float* __restrict__ G, float* __restrict__ P){
  __shared__ __align__(16) float Fs[32*128];   // 16 KB
  __shared__ __align__(16) float Ws[32*64];    // 8 KB
  const int img = blockIdx.y;
  const int u   = blockIdx.x;                  // 144 blocks/img, all equal work
  const float* feat; int C, HW, Woff, tile, split; long pbase; bool multi;
  if (u < 16)      { feat=f4; C=1024; HW=144;  Woff=896; tile=u>>3;      split=u&7;
                     pbase=P4_BASE + (long)split*P4_SLAB; multi=true;  }
  else if (u < 36) { feat=f3; C=512;  HW=576;  Woff=384; tile=(u-16)>>2; split=(u-16)&3;
                     pbase=P3_BASE + (long)split*P3_SLAB; multi=true;  }
  else if (u < 72) { feat=f2; C=256;  HW=2304; Woff=128; tile=(u-36)>>1; split=(u-36)&1;
                     pbase=P2_BASE + (long)split*P2_SLAB; multi=true;  }
  else             { feat=f1; C=128;  HW=9216; Woff=0;   tile=u-72;      split=0;
                     pbase=0; multi=false; }
  const int px0  = tile*128;
  const int hw4  = HW >> 2;
  const int px04 = px0 >> 2;
  const int tid  = threadIdx.x;
  const int tx   = tid & 15;        // px group (8 px: quads tx and tx+16)
  const int ty   = tid >> 4;        // j group  (4 j)
  const int c0b  = split*128;
  const float4* feat4 = (const float4*)feat;
  const float4* W14   = (const float4*)W1;
  float4* Fs4 = (float4*)Fs;
  float4* Ws4 = (float4*)Ws;
  const long fbase = (long)img*C*hw4;
  float4 rF[4]; float4 rW[2];
  float4 a0 = make_float4(0.f,0.f,0.f,0.f), a1 = a0, a2 = a0, a3 = a0;
  float4 a4 = a0, a5 = a0, a6 = a0, a7 = a0;

  load_chunk(feat4, W14, fbase, hw4, px04, Woff, c0b, tid, rF, rW);
  for (int ch = 0; ch < 4; ch++){
    __syncthreads();                           // prev compute done -> LDS reusable
    #pragma unroll
    for (int k = 0; k < 4; k++) Fs4[tid + k*256] = rF[k];
    #pragma unroll
    for (int k = 0; k < 2; k++) Ws4[tid + k*256] = rW[k];
    if (ch < 3)                                // prefetch next chunk under compute
      load_chunk(feat4, W14, fbase, hw4, px04, Woff, c0b + (ch+1)*32, tid, rF, rW);
    __syncthreads();
    #pragma unroll 8
    for (int c = 0; c < 32; c++){
      float4 fa = Fs4[c*32 + tx];
      float4 fb = Fs4[c*32 + 16 + tx];
      float4 wv = Ws4[c*16 + ty];
      FMA_ROW(fa.x, a0) FMA_ROW(fa.y, a1) FMA_ROW(fa.z, a2) FMA_ROW(fa.w, a3)
      FMA_ROW(fb.x, a4) FMA_ROW(fb.y, a5) FMA_ROW(fb.z, a6) FMA_ROW(fb.w, a7)
    }
  }
  float* outb = multi ? (P + pbase + (long)img*HW*64)
                      : (G + (long)img*HW*64);           // L1 region starts at G+0
  const int pxa = px0 + tx*4;
#define STOREQ(A, GP) do { int gp = (GP); if (gp < HW){ \
    *(float4*)(outb + (long)gp*64 + ty*4) = A; } } while(0)
  STOREQ(a0, pxa + 0);  STOREQ(a1, pxa + 1);
  STOREQ(a2, pxa + 2);  STOREQ(a3, pxa + 3);
  STOREQ(a4, pxa + 64); STOREQ(a5, pxa + 65);
  STOREQ(a6, pxa + 66); STOREQ(a7, pxa + 67);
#undef STOREQ
}

// ---------------- K5b: sum split-K partial slabs into final G (L2-L4 region) ----
__global__ __launch_bounds__(256) void k_reduce(const float4* __restrict__ P4f,
                                                float4* __restrict__ G4f){
  const int N2 = P2_SLAB/4;   // 294912 f4
  const int N3 = P3_SLAB/4;   // 73728  f4
  const int N4 = P4_SLAB/4;   // 18432  f4
  int t = blockIdx.x*256 + threadIdx.x;
  if (t < N2){
    float4 a = P4f[t];
    float4 b = P4f[N2 + t];
    float4 r = make_float4(a.x+b.x, a.y+b.y, a.z+b.z, a.w+b.w);
    G4f[G2_OFF/4 + t] = r;
  } else if (t < N2 + N3){
    int u = t - N2;
    const float4* base = P4f + P3_BASE/4 + u;
    float4 r = base[0];
    #pragma unroll
    for (int s = 1; s < 4; s++){
      float4 b = base[(long)s*N3];
      r.x += b.x; r.y += b.y; r.z += b.z; r.w += b.w;
    }
    G4f[G3_OFF/4 + u] = r;
  } else if (t < N2 + N3 + N4){
    int u = t - N2 - N3;
    const float4* base = P4f + P4_BASE/4 + u;
    float4 r = base[0];
    #pragma unroll
    for (int s = 1; s < 8; s++){
      float4 b = base[(long)s*N4];
      r.x += b.x; r.y += b.y; r.z += b.z; r.w += b.w;
    }
    G4f[G4_OFF/4 + u] = r;
  }
}

// ---------------- K6: fused ROI-gather + bias + leaky + layer2 + assembly ----------------
__device__ __forceinline__ void roi_level(const float* __restrict__ g,
    int Hl, int Wl, float scale, float x1, float y1, float x2, float y2,
    int lane, float& h){
  float bx1=x1*scale, by1=y1*scale, bx2=x2*scale, by2=y2*scale;
  float rw=fmaxf(bx2-bx1,1.f), rh=fmaxf(by2-by1,1.f);
  float ys[2]={by1+rh*0.25f, by1+rh*0.75f};
  float xs[2]={bx1+rw*0.25f, bx1+rw*0.75f};
  #pragma unroll
  for (int pt = 0; pt < 4; pt++){
    float y=ys[pt>>1], x=xs[pt&1];
    if ((y>-1.f)&&(y<(float)Hl)&&(x>-1.f)&&(x<(float)Wl)){   // wave-uniform branch
      float yc=fmaxf(y,0.f), xc=fmaxf(x,0.f);
      int y0=(int)fminf(floorf(yc),(float)(Hl-1));
      int x0=(int)fminf(floorf(xc),(float)(Wl-1));
      int y1i=min(y0+1,Hl-1), x1i=min(x0+1,Wl-1);
      float ly=yc-(float)y0, lx=xc-(float)x0;
      float hy=1.f-ly, hx=1.f-lx;
      h += (hy*hx*0.25f)*g[(long)(y0*Wl+x0)*64+lane];
      h += (hy*lx*0.25f)*g[(long)(y0*Wl+x1i)*64+lane];
      h += (ly*hx*0.25f)*g[(long)(y1i*Wl+x0)*64+lane];
      h += (ly*lx*0.25f)*g[(long)(y1i*Wl+x1i)*64+lane];
    }
  }
}

__global__ __launch_bounds__(256) void k_roi_mlp(const float* __restrict__ G,
    const float* __restrict__ selbox, const u32* __restrict__ selcnt,
    const float* __restrict__ b1, const float* __restrict__ W2,
    const float* __restrict__ b2, float* __restrict__ out){
  const int img  = blockIdx.y;
  const int wave = threadIdx.x >> 6;
  const int lane = threadIdx.x & 63;
  const int slot = blockIdx.x*4 + wave;
  if (slot >= MAXDET) return;
  float* o = out + ((long)img*MAXDET + slot)*68;
  if (slot >= (int)selcnt[img]){
    o[4+lane] = 0.f;
    if (lane < 4) o[lane] = 0.f;
    return;
  }
  const float* sb = selbox + ((long)img*MAXDET + slot)*4;
  float x1 = sb[0], y1 = sb[1], x2 = sb[2], y2 = sb[3];
  const float* Gi1 = G +          (long)img*9216*64;
  const float* Gi2 = G + G2_OFF + (long)img*2304*64;
  const float* Gi3 = G + G3_OFF + (long)img*576*64;
  const float* Gi4 = G + G4_OFF + (long)img*144*64;
  float h = 0.f;
  roi_level(Gi1, 96, 96, 0.125f,    x1,y1,x2,y2, lane, h);
  roi_level(Gi2, 48, 48, 0.0625f,   x1,y1,x2,y2, lane, h);
  roi_level(Gi3, 24, 24, 0.03125f,  x1,y1,x2,y2, lane, h);
  roi_level(Gi4, 12, 12, 0.015625f, x1,y1,x2,y2, lane, h);
  float h1 = leaky(h + b1[lane]);
  float c = 0.f;
  #pragma unroll 8
  for (int k = 0; k < 64; k++){
    float hk = __shfl(h1, k, 64);
    c += hk * W2[k*64 + lane];
  }
  o[4+lane] = leaky(c + b2[lane]);
  if (lane < 4) o[lane] = sb[lane] / 768.0f;
}

// ---------------- workspace layout (bytes) ----------------
// 0        hist    u32[8][2048]        65536
// 65536    cnt     u32[8]              256 (padded)
// 65792    kmask   u64[8][8]           512
// 66304    thr     u32[8]              256
// 66560    selbox  f32[8][300][4]      38400
// 104960   selcnt  u32[8]              256
// 105216   sbits   u32[8][36720]       1175040
// 1280256  cls     i32[8][36720]       1175040
// 2455296  cand    u64[8][1024]        65536
// 2520832  cbs_g   f4[8][512]          65536
// 2586368  obs_g   f4[8][512]          65536
// 2651904  lrows_g u64[8][512][8]      262144
// 2914048  G       f32 level-major     25067520
// 27981568 P       f32 partials        16515072   -> total ~44.5 MB
#define WS_G 2914048
#define WS_P 27981568

extern "C" void kernel_launch(void* const* d_in, const int* in_sizes, int n_in,
                              void* d_out, int out_size, void* d_ws, size_t ws_size,
                              hipStream_t stream){
  const float* preds = (const float*)d_in[0];
  const float* f1 = (const float*)d_in[1];
  const float* f2 = (const float*)d_in[2];
  const float* f3 = (const float*)d_in[3];
  const float* f4 = (const float*)d_in[4];
  const float* W1 = (const float*)d_in[5];
  const float* b1 = (const float*)d_in[6];
  const float* W2 = (const float*)d_in[7];
  const float* b2 = (const float*)d_in[8];
  float* out = (float*)d_out;
  char* ws = (char*)d_ws;
  u32* hist    = (u32*)(ws + 0);
  u32* cnt     = (u32*)(ws + 65536);
  u64* kmask_g = (u64*)(ws + 65792);
  u32* thr     = (u32*)(ws + 66304);
  float* selb  = (float*)(ws + 66560);
  u32* selc    = (u32*)(ws + 104960);
  u32* sbits   = (u32*)(ws + 105216);
  int* clsA    = (int*)(ws + 1280256);
  u64* cand    = (u64*)(ws + 2455296);
  float4* cbs_g = (float4*)(ws + 2520832);
  float4* obs_g = (float4*)(ws + 2586368);
  u64* lrows_g  = (u64*)(ws + 2651904);
  float* G     = (float*)(ws + WS_G);
  float* P     = (float*)(ws + WS_P);

  hipMemsetAsync(ws, 0, 66304, stream);                 // hist + cnt + kmask

  dim3 gs((NCAND + 255)/256, B_IMG);
  k_score<<<gs, 256, 0, stream>>>(preds, sbits, clsA, hist);
  k_thresh<<<B_IMG, 64, 0, stream>>>(hist, thr);
  dim3 g3((NCAND+255)/256, B_IMG);
  k_gather<<<g3, 256, 0, stream>>>(sbits, thr, cnt, cand);
  k_rank<<<B_IMG*4, 256, 0, stream>>>(preds, clsA, cand, cnt, cbs_g, obs_g, kmask_g);
  k_iou<<<B_IMG*8, 512, 0, stream>>>(cbs_g, kmask_g, lrows_g);
  k_greedy<<<B_IMG, 512, 0, stream>>>(lrows_g, kmask_g, obs_g, selb, selc);
  k_proj<<<dim3(144, B_IMG), 256, 0, stream>>>(f1, f2, f3, f4, W1, G, P);
  // reduce L2-L4 partial slabs into final G: (294912+73728+18432) f4 / 256
  k_reduce<<<1512, 256, 0, stream>>>((const float4*)P, (float4*)G);
  k_roi_mlp<<<dim3((MAXDET+3)/4, B_IMG), 256, 0, stream>>>(G, selb, selc, b1, W2, b2, out);
}

// Round 5
// 358.437 us; speedup vs baseline: 1.2584x; 1.0028x over previous
//
#include <hip/hip_runtime.h>
#include <cstdint>

#define B_IMG   8
#define NCAND   36720
#define PD      85
#define NCLS    80
#define KC      512
#define MAXDET  300
#define NBUCK   2048
#define CANDCAP 1024      // gathered count is ~512 + one-bucket (<~40): 1024 is safe

// G (fp32, level-major) float offsets: L1[8][9216][64] | L2[8][2304][64] | L3[8][576][64] | L4[8][144][64]
#define G2_OFF 4718592
#define G3_OFF 5898240
#define G4_OFF 6193152
#define G_TOT  6266880

// Partial-sum buffer P (float offsets within P)
#define P2_BASE 0
#define P2_SLAB 1179648
#define P3_BASE 2359296
#define P3_SLAB 294912
#define P4_BASE 3538944
#define P4_SLAB 73728

typedef unsigned int u32;
typedef unsigned long long u64;

__device__ __forceinline__ float leaky(float x){ return x >= 0.f ? x : 0.01f*x; }

__device__ __forceinline__ u64 shfl_u64(u64 v, int lane){
  int lo = __shfl((int)(u32)(v & 0xFFFFFFFFull), lane, 64);
  int hi = __shfl((int)(u32)(v >> 32), lane, 64);
  return ((u64)(u32)hi << 32) | (u64)(u32)lo;
}
__device__ __forceinline__ u64 shfl_xor_u64(u64 v, int mask){
  int lo = __shfl_xor((int)(u32)(v & 0xFFFFFFFFull), mask, 64);
  int hi = __shfl_xor((int)(u32)(v >> 32), mask, 64);
  return ((u64)(u32)hi << 32) | (u64)(u32)lo;
}

// ---------------- K1: two-phase score: obj-filter -> class-scan survivors only ----
__global__ __launch_bounds__(256) void k_score(const float* __restrict__ preds,
    u32* __restrict__ sbits, int* __restrict__ clsArr, u32* __restrict__ hist){
  __shared__ u32   sl_lane[4][64];
  __shared__ float sl_obj[4][64];
  __shared__ u32   sl_res[4][64];
  __shared__ u32   sl_cls[4][64];
  const int img  = blockIdx.y;
  const int wv   = threadIdx.x >> 6;
  const int lane = threadIdx.x & 63;
  const int base = (blockIdx.x*4 + wv)*64;
  const int ci   = base + lane;
  const bool inb = ci < NCAND;
  float obj = 0.f;
  if (inb) obj = preds[((long)img*NCAND + ci)*PD + 4];
  const bool pass = obj > 0.596f;
  u64 mask = __ballot(pass);
  int cnt  = __popcll(mask);
  int rank = __popcll(mask & ((1ull << lane) - 1ull));
  if (pass){ sl_lane[wv][rank] = (u32)lane; sl_obj[wv][rank] = obj; }
  const int q = lane & 3;
  for (int r0 = 0; r0 < cnt; r0 += 16){
    int idx = r0 + (lane >> 2);
    if (idx < cnt){
      u32 sl = sl_lane[wv][idx];
      float obj2 = sl_obj[wv][idx];
      const float* p2 = preds + ((long)img*NCAND + base + (int)sl)*PD + 5 + q;
      u64 best = 0ull;
      #pragma unroll
      for (int k = 0; k < 20; k++){
        float v = p2[4*k] * obj2;                       // exact ref: cls*obj
        u64 key = ((u64)__float_as_uint(v) << 32) | (u64)(~(u32)(q + 4*k));
        if (key > best) best = key;                     // first max wins
      }
      u64 o1 = shfl_xor_u64(best, 1); if (o1 > best) best = o1;
      u64 o2 = shfl_xor_u64(best, 2); if (o2 > best) best = o2;
      if (q == 0){
        u32 bits = (u32)(best >> 32);
        sl_res[wv][sl] = (__uint_as_float(bits) > 0.596f) ? bits : 0u;
        sl_cls[wv][sl] = ~(u32)(best & 0xFFFFFFFFull);
      }
    }
  }
  if (inb){
    u32 out = pass ? sl_res[wv][lane] : 0u;             // valid scores in (0.596,1)
    sbits[(long)img*NCAND + ci] = out;
    if (pass) clsArr[(long)img*NCAND + ci] = (int)sl_cls[wv][lane];
    if (out) atomicAdd(&hist[img*NBUCK + ((out - 0x3F000000u) >> 12)], 1u);
  }
}

// ---------------- K2: per-image bit-threshold covering top-512 ----------------
__global__ __launch_bounds__(64) void k_thresh(const u32* __restrict__ hist,
                                               u32* __restrict__ thr){
  const int img = blockIdx.x;
  const int lane = threadIdx.x;
  const u32* h = hist + img*NBUCK;
  u32 acc = 0; u32 result = 0x3F000000u; bool found = false;
  for (int g = NBUCK/64 - 1; g >= 0 && !found; g--){
    u32 v = h[g*64 + lane];
    u32 s = v;
    #pragma unroll
    for (int off = 1; off < 64; off <<= 1){
      u32 t = __shfl_down(s, off, 64);
      s += (lane + off < 64) ? t : 0u;
    }
    u64 mask = __ballot(acc + s >= KC);
    if (mask){
      int hl = 63 - __clzll(mask);
      result = 0x3F000000u + ((u32)(g*64 + hl) << 12);
      found = true;
    }
    acc += __shfl(s, 0, 64);
  }
  if (lane == 0) thr[img] = result;
}

// ---------------- K3: gather candidates >= threshold as sortable keys ----------------
__global__ __launch_bounds__(256) void k_gather(const u32* __restrict__ sbits,
    const u32* __restrict__ thr, u32* __restrict__ cnt, u64* __restrict__ cand){
  int img = blockIdx.y;
  int n = blockIdx.x*256 + threadIdx.x;
  if (n >= NCAND) return;
  u32 bits = sbits[(long)img*NCAND + n];
  if (bits && bits >= thr[img]){
    u32 pos = atomicAdd(&cnt[img], 1u);
    if (pos < CANDCAP)
      cand[(long)img*CANDCAP + pos] = ((u64)bits << 32) | (u64)(0xFFFFFFFFu - (u32)n);
  }
}

// ---------------- K4a: rank + decode ranked boxes to global ----------------
__global__ __launch_bounds__(256) void k_rank(const float* __restrict__ preds,
    const int* __restrict__ clsArr, const u64* __restrict__ cand,
    const u32* __restrict__ cnt, float4* __restrict__ cbs_g,
    float4* __restrict__ obs_g, u64* __restrict__ kmask_g){
#pragma clang fp contract(off)
  __shared__ __align__(16) u64 keys[CANDCAP];      // 8 KB
  const int img = blockIdx.x >> 2;
  const int sub = blockIdx.x & 3;
  const int tid = threadIdx.x;
  const int M = min((int)cnt[img], CANDCAP);
  #pragma unroll
  for (int k = 0; k < 4; k++){
    int s = k*256 + tid;
    keys[s] = (s < M) ? cand[(long)img*CANDCAP + s] : 0ull;
  }
  __syncthreads();
  const int slot = sub*256 + tid;
  u64 k0 = keys[slot];
  int r0 = 0;
  const ulonglong2* kv = (const ulonglong2*)keys;
  for (int j = 0; j < CANDCAP/2; j++){              // wave-uniform b128 broadcast
    ulonglong2 kk = kv[j];
    r0 += (kk.x > k0) + (kk.y > k0);
  }
  if ((k0 >> 32) != 0ull && r0 < KC){
    u32 idxn = 0xFFFFFFFFu - (u32)(k0 & 0xFFFFFFFFull);
    const float* p = preds + ((long)img*NCAND + idxn)*PD;
    float cx = p[0], cy = p[1], w = p[2], h = p[3];
    float hw = w*0.5f, hh = h*0.5f;                 // exact
    float X1 = cx-hw, Y1 = cy-hh, X2 = cx+hw, Y2 = cy+hh;
    float off = (float)clsArr[(long)img*NCAND + idxn] * 4096.0f;  // exact
    obs_g[(long)img*KC + r0] = make_float4(X1, Y1, X2, Y2);
    cbs_g[(long)img*KC + r0] = make_float4(X1+off, Y1+off, X2+off, Y2+off);
    atomicOr(&kmask_g[img*8 + (r0 >> 6)], 1ull << (r0 & 63));
  }
}

// ---------------- K4b: IOU suppression matrix, 64 rows x 512 cols per block ----
__global__ __launch_bounds__(512) void k_iou(const float4* __restrict__ cbs_g,
    const u64* __restrict__ kmask_g, u64* __restrict__ lrows_g){
#pragma clang fp contract(off)
  __shared__ __align__(16) float4 cbsL[8*65];      // stride-65 swizzle: conflict-free
  const int img = blockIdx.x >> 3;
  const int ch  = blockIdx.x & 7;
  const int tid = threadIdx.x;
  if (tid < KC){
    u64 km = kmask_g[img*8 + (tid >> 6)];
    bool f = (km >> (tid & 63)) & 1ull;
    float4 v = f ? cbs_g[(long)img*KC + tid]
                 : make_float4(-4e8f, -4e8f, -4e8f, -4e8f);  // zero-area -> iou 0
    cbsL[(tid >> 6)*65 + (tid & 63)] = v;
  }
  __syncthreads();
  const int row = ch*64 + (tid >> 3);
  const int w   = tid & 7;
  float4 bi = cbsL[(row >> 6)*65 + (row & 63)];
  float areai = (bi.z - bi.x)*(bi.w - bi.y);
  u64 bits = 0ull;
  const int jbase = w*64;
  for (int b = 0; b < 64; b++){
    int j = jbase + b;
    if (j > row){
      float4 bj = cbsL[w*65 + b];
      float areaj = (bj.z - bj.x)*(bj.w - bj.y);
      float ltx = fmaxf(bi.x, bj.x), lty = fmaxf(bi.y, bj.y);
      float rbx = fminf(bi.z, bj.z), rby = fminf(bi.w, bj.w);
      float ww = fmaxf(rbx - ltx, 0.f);
      float hh = fmaxf(rby - lty, 0.f);
      float inter = ww*hh;
      float iou = inter / (areai + areaj - inter + 1e-7f);  // exact ref op order
      if (iou > 0.45f) bits |= (1ull << b);
    }
  }
  lrows_g[((long)img*KC + row)*8 + w] = bits;      // coalesced 8B stores
}

// ---------------- K4c: greedy suppression (serial core) + compact ----------------
__global__ __launch_bounds__(512) void k_greedy(const u64* __restrict__ lrows_g,
    const u64* __restrict__ kmask_g, const float4* __restrict__ obs_g,
    float* __restrict__ selbox, u32* __restrict__ selcnt){
  __shared__ __align__(16) u64 lrows[KC*8];        // 32 KB
  __shared__ u64 keepw[8];
  const int img = blockIdx.x;
  const int tid = threadIdx.x;
  const ulonglong2* src = (const ulonglong2*)(lrows_g + (long)img*KC*8);
  ulonglong2* dst = (ulonglong2*)lrows;
  #pragma unroll
  for (int k = 0; k < 4; k++) dst[k*512 + tid] = src[k*512 + tid];
  __syncthreads();
  if (tid < 64){
    const int lane = tid;
    const int w = lane & 7;
    u64 kw_own = kmask_g[img*8 + w];
    for (int b = 0; b < 8; b++){
      u64 kwb = shfl_u64(kw_own, b);
      for (int g = 0; g < 8; g++){
        u64 rdec[8], rown[8];
        #pragma unroll
        for (int k = 0; k < 8; k++){
          int i = b*64 + g*8 + k;
          rdec[k] = lrows[i*8 + b];
          rown[k] = lrows[i*8 + w];
        }
        #pragma unroll
        for (int k = 0; k < 8; k++){
          int il = g*8 + k;
          if ((kwb >> il) & 1ull){
            kwb    &= ~rdec[k];
            kw_own &= ~rown[k];
          }
        }
      }
    }
    if (lane < 8) keepw[lane] = kw_own;
  }
  __syncthreads();
  {
    u64 kk[8];
    #pragma unroll
    for (int w = 0; w < 8; w++) kk[w] = keepw[w];
    const int s = tid;
    const int wi = s >> 6, bi = s & 63;
    bool kept = (kk[wi] >> bi) & 1ull;
    if (kept){
      int rank = 0;
      for (int w = 0; w < wi; w++) rank += __popcll(kk[w]);
      rank += __popcll(bi ? (kk[wi] & ((1ull << bi) - 1ull)) : 0ull);
      if (rank < MAXDET){
        float4 ob = obs_g[(long)img*KC + s];
        float* sb = selbox + ((long)img*MAXDET + rank)*4;
        sb[0]=ob.x; sb[1]=ob.y; sb[2]=ob.z; sb[3]=ob.w;
      }
    }
    if (tid == 0){
      int tot = 0;
      #pragma unroll
      for (int w = 0; w < 8; w++) tot += __popcll(kk[w]);
      selcnt[img] = (u32)min(tot, MAXDET);
    }
  }
}

// ---------------- K5: projection GEMM, split-K balanced, coalesced epilogue ----
// R11: R10's WRITE_SIZE was 133MB vs ~36MB useful (x3.7). Store pattern was
// 64 scattered 16B chunks per wave-store (j mapped to tid>>4): partial-sector
// writes that don't merge before TCC->EA get padded to full sectors. Fix: j
// is now the LANE-FAST axis (jg = tid&15, pg = tid>>4): each wave-store = 4
// contiguous 256B runs (16 lanes x 16B), fully line-aligned. Same arithmetic
// per output element (bit-identical); Fs reads become 4-addr broadcast
// (conflict-free), Ws reads 2-way aliased (free, m136). launch_bounds(256,2)
// rules out allocator spills (VGPR headroom to 256).
__device__ __forceinline__ void load_chunk(const float4* __restrict__ feat4,
    const float4* __restrict__ W14, long fbase, int hw4, int px04, int Woff,
    int c0, int tid, float4 (&rF)[4], float4 (&rW)[2]){
  #pragma unroll
  for (int k = 0; k < 4; k++){
    int s = tid + k*256; int c = s >> 5, q = s & 31;
    int pq = px04 + q; if (pq >= hw4) pq = hw4 - 1;   // ragged tile clamp (stores guarded)
    rF[k] = feat4[fbase + (long)(c0 + c)*hw4 + pq];
  }
  #pragma unroll
  for (int k = 0; k < 2; k++){
    int s = tid + k*256; int c = s >> 4, q = s & 15;
    rW[k] = W14[(long)(Woff + c0 + c)*16 + q];
  }
}

#define FMA_ROW(S, A) \
  A.x = fmaf(S, wv.x, A.x); A.y = fmaf(S, wv.y, A.y); \
  A.z = fmaf(S, wv.z, A.z); A.w = fmaf(S, wv.w, A.w);

__global__ __launch_bounds__(256, 2) void k_proj(const float* __restrict__ f1,
    const float* __restrict__ f2, const float* __restrict__ f3,
    const float* __restrict__ f4, const float* __restrict__ W1,
    float* __restrict__ G, float* __restrict__ P){
  __shared__ __align__(16) float Fs[32*128];   // 16 KB
  __shared__ __align__(16) float Ws[32*64];    // 8 KB
  const int img = blockIdx.y;
  const int u   = blockIdx.x;                  // 144 blocks/img, all equal work
  const float* feat; int C, HW, Woff, tile, split; long pbase; bool multi;
  if (u < 16)      { feat=f4; C=1024; HW=144;  Woff=896; tile=u>>3;      split=u&7;
                     pbase=P4_BASE + (long)split*P4_SLAB; multi=true;  }
  else if (u < 36) { feat=f3; C=512;  HW=576;  Woff=384; tile=(u-16)>>2; split=(u-16)&3;
                     pbase=P3_BASE + (long)split*P3_SLAB; multi=true;  }
  else if (u < 72) { feat=f2; C=256;  HW=2304; Woff=128; tile=(u-36)>>1; split=(u-36)&1;
                     pbase=P2_BASE + (long)split*P2_SLAB; multi=true;  }
  else             { feat=f1; C=128;  HW=9216; Woff=0;   tile=u-72;      split=0;
                     pbase=0; multi=false; }
  const int px0  = tile*128;
  const int hw4  = HW >> 2;
  const int px04 = px0 >> 2;
  const int tid  = threadIdx.x;
  const int jg   = tid & 15;        // j group: j = jg*4..jg*4+3  (lane-fast axis)
  const int pg   = tid >> 4;        // px group: px = px0 + pg*8 + p, p=0..7
  const int c0b  = split*128;
  const float4* feat4 = (const float4*)feat;
  const float4* W14   = (const float4*)W1;
  float4* Fs4 = (float4*)Fs;
  float4* Ws4 = (float4*)Ws;
  const long fbase = (long)img*C*hw4;
  float4 rF[4]; float4 rW[2];
  float4 a0 = make_float4(0.f,0.f,0.f,0.f), a1 = a0, a2 = a0, a3 = a0;
  float4 a4 = a0, a5 = a0, a6 = a0, a7 = a0;

  load_chunk(feat4, W14, fbase, hw4, px04, Woff, c0b, tid, rF, rW);
  for (int ch = 0; ch < 4; ch++){
    __syncthreads();                           // prev compute done -> LDS reusable
    #pragma unroll
    for (int k = 0; k < 4; k++) Fs4[tid + k*256] = rF[k];
    #pragma unroll
    for (int k = 0; k < 2; k++) Ws4[tid + k*256] = rW[k];
    if (ch < 3)                                // prefetch next chunk under compute
      load_chunk(feat4, W14, fbase, hw4, px04, Woff, c0b + (ch+1)*32, tid, rF, rW);
    __syncthreads();
    #pragma unroll 8
    for (int c = 0; c < 32; c++){
      float4 fa = Fs4[c*32 + pg*2];        // px pg*8..pg*8+3 (16-lane broadcast)
      float4 fb = Fs4[c*32 + pg*2 + 1];    // px pg*8+4..pg*8+7
      float4 wv = Ws4[c*16 + jg];          // j jg*4..jg*4+3 (2-way aliased: free)
      FMA_ROW(fa.x, a0) FMA_ROW(fa.y, a1) FMA_ROW(fa.z, a2) FMA_ROW(fa.w, a3)
      FMA_ROW(fb.x, a4) FMA_ROW(fb.y, a5) FMA_ROW(fb.z, a6) FMA_ROW(fb.w, a7)
    }
  }
  float* outb = multi ? (P + pbase + (long)img*HW*64)
                      : (G + (long)img*HW*64);           // L1 region starts at G+0
  const int pxa = px0 + pg*8;
#define STOREQ(A, PP) do { int gp = pxa + (PP); if (gp < HW){ \
    *(float4*)(outb + (long)gp*64 + jg*4) = A; } } while(0)
  STOREQ(a0, 0); STOREQ(a1, 1); STOREQ(a2, 2); STOREQ(a3, 3);
  STOREQ(a4, 4); STOREQ(a5, 5); STOREQ(a6, 6); STOREQ(a7, 7);
#undef STOREQ
}

// ---------------- K5b: sum split-K partial slabs into final G (L2-L4 region) ----
__global__ __launch_bounds__(256) void k_reduce(const float4* __restrict__ P4f,
                                                float4* __restrict__ G4f){
  const int N2 = P2_SLAB/4;   // 294912 f4
  const int N3 = P3_SLAB/4;   // 73728  f4
  const int N4 = P4_SLAB/4;   // 18432  f4
  int t = blockIdx.x*256 + threadIdx.x;
  if (t < N2){
    float4 a = P4f[t];
    float4 b = P4f[N2 + t];
    float4 r = make_float4(a.x+b.x, a.y+b.y, a.z+b.z, a.w+b.w);
    G4f[G2_OFF/4 + t] = r;
  } else if (t < N2 + N3){
    int u = t - N2;
    const float4* base = P4f + P3_BASE/4 + u;
    float4 r = base[0];
    #pragma unroll
    for (int s = 1; s < 4; s++){
      float4 b = base[(long)s*N3];
      r.x += b.x; r.y += b.y; r.z += b.z; r.w += b.w;
    }
    G4f[G3_OFF/4 + u] = r;
  } else if (t < N2 + N3 + N4){
    int u = t - N2 - N3;
    const float4* base = P4f + P4_BASE/4 + u;
    float4 r = base[0];
    #pragma unroll
    for (int s = 1; s < 8; s++){
      float4 b = base[(long)s*N4];
      r.x += b.x; r.y += b.y; r.z += b.z; r.w += b.w;
    }
    G4f[G4_OFF/4 + u] = r;
  }
}

// ---------------- K6: fused ROI-gather + bias + leaky + layer2 + assembly ----------------
__device__ __forceinline__ void roi_level(const float* __restrict__ g,
    int Hl, int Wl, float scale, float x1, float y1, float x2, float y2,
    int lane, float& h){
  float bx1=x1*scale, by1=y1*scale, bx2=x2*scale, by2=y2*scale;
  float rw=fmaxf(bx2-bx1,1.f), rh=fmaxf(by2-by1,1.f);
  float ys[2]={by1+rh*0.25f, by1+rh*0.75f};
  float xs[2]={bx1+rw*0.25f, bx1+rw*0.75f};
  #pragma unroll
  for (int pt = 0; pt < 4; pt++){
    float y=ys[pt>>1], x=xs[pt&1];
    if ((y>-1.f)&&(y<(float)Hl)&&(x>-1.f)&&(x<(float)Wl)){   // wave-uniform branch
      float yc=fmaxf(y,0.f), xc=fmaxf(x,0.f);
      int y0=(int)fminf(floorf(yc),(float)(Hl-1));
      int x0=(int)fminf(floorf(xc),(float)(Wl-1));
      int y1i=min(y0+1,Hl-1), x1i=min(x0+1,Wl-1);
      float ly=yc-(float)y0, lx=xc-(float)x0;
      float hy=1.f-ly, hx=1.f-lx;
      h += (hy*hx*0.25f)*g[(long)(y0*Wl+x0)*64+lane];
      h += (hy*lx*0.25f)*g[(long)(y0*Wl+x1i)*64+lane];
      h += (ly*hx*0.25f)*g[(long)(y1i*Wl+x0)*64+lane];
      h += (ly*lx*0.25f)*g[(long)(y1i*Wl+x1i)*64+lane];
    }
  }
}

__global__ __launch_bounds__(256) void k_roi_mlp(const float* __restrict__ G,
    const float* __restrict__ selbox, const u32* __restrict__ selcnt,
    const float* __restrict__ b1, const float* __restrict__ W2,
    const float* __restrict__ b2, float* __restrict__ out){
  const int img  = blockIdx.y;
  const int wave = threadIdx.x >> 6;
  const int lane = threadIdx.x & 63;
  const int slot = blockIdx.x*4 + wave;
  if (slot >= MAXDET) return;
  float* o = out + ((long)img*MAXDET + slot)*68;
  if (slot >= (int)selcnt[img]){
    o[4+lane] = 0.f;
    if (lane < 4) o[lane] = 0.f;
    return;
  }
  const float* sb = selbox + ((long)img*MAXDET + slot)*4;
  float x1 = sb[0], y1 = sb[1], x2 = sb[2], y2 = sb[3];
  const float* Gi1 = G +          (long)img*9216*64;
  const float* Gi2 = G + G2_OFF + (long)img*2304*64;
  const float* Gi3 = G + G3_OFF + (long)img*576*64;
  const float* Gi4 = G + G4_OFF + (long)img*144*64;
  float h = 0.f;
  roi_level(Gi1, 96, 96, 0.125f,    x1,y1,x2,y2, lane, h);
  roi_level(Gi2, 48, 48, 0.0625f,   x1,y1,x2,y2, lane, h);
  roi_level(Gi3, 24, 24, 0.03125f,  x1,y1,x2,y2, lane, h);
  roi_level(Gi4, 12, 12, 0.015625f, x1,y1,x2,y2, lane, h);
  float h1 = leaky(h + b1[lane]);
  float c = 0.f;
  #pragma unroll 8
  for (int k = 0; k < 64; k++){
    float hk = __shfl(h1, k, 64);
    c += hk * W2[k*64 + lane];
  }
  o[4+lane] = leaky(c + b2[lane]);
  if (lane < 4) o[lane] = sb[lane] / 768.0f;
}

// ---------------- workspace layout (bytes) ----------------
// 0        hist    u32[8][2048]        65536
// 65536    cnt     u32[8]              256 (padded)
// 65792    kmask   u64[8][8]           512
// 66304    thr     u32[8]              256
// 66560    selbox  f32[8][300][4]      38400
// 104960   selcnt  u32[8]              256
// 105216   sbits   u32[8][36720]       1175040
// 1280256  cls     i32[8][36720]       1175040
// 2455296  cand    u64[8][1024]        65536
// 2520832  cbs_g   f4[8][512]          65536
// 2586368  obs_g   f4[8][512]          65536
// 2651904  lrows_g u64[8][512][8]      262144
// 2914048  G       f32 level-major     25067520
// 27981568 P       f32 partials        16515072   -> total ~44.5 MB
#define WS_G 2914048
#define WS_P 27981568

extern "C" void kernel_launch(void* const* d_in, const int* in_sizes, int n_in,
                              void* d_out, int out_size, void* d_ws, size_t ws_size,
                              hipStream_t stream){
  const float* preds = (const float*)d_in[0];
  const float* f1 = (const float*)d_in[1];
  const float* f2 = (const float*)d_in[2];
  const float* f3 = (const float*)d_in[3];
  const float* f4 = (const float*)d_in[4];
  const float* W1 = (const float*)d_in[5];
  const float* b1 = (const float*)d_in[6];
  const float* W2 = (const float*)d_in[7];
  const float* b2 = (const float*)d_in[8];
  float* out = (float*)d_out;
  char* ws = (char*)d_ws;
  u32* hist    = (u32*)(ws + 0);
  u32* cnt     = (u32*)(ws + 65536);
  u64* kmask_g = (u64*)(ws + 65792);
  u32* thr     = (u32*)(ws + 66304);
  float* selb  = (float*)(ws + 66560);
  u32* selc    = (u32*)(ws + 104960);
  u32* sbits   = (u32*)(ws + 105216);
  int* clsA    = (int*)(ws + 1280256);
  u64* cand    = (u64*)(ws + 2455296);
  float4* cbs_g = (float4*)(ws + 2520832);
  float4* obs_g = (float4*)(ws + 2586368);
  u64* lrows_g  = (u64*)(ws + 2651904);
  float* G     = (float*)(ws + WS_G);
  float* P     = (float*)(ws + WS_P);

  hipMemsetAsync(ws, 0, 66304, stream);                 // hist + cnt + kmask

  dim3 gs((NCAND + 255)/256, B_IMG);
  k_score<<<gs, 256, 0, stream>>>(preds, sbits, clsA, hist);
  k_thresh<<<B_IMG, 64, 0, stream>>>(hist, thr);
  dim3 g3((NCAND+255)/256, B_IMG);
  k_gather<<<g3, 256, 0, stream>>>(sbits, thr, cnt, cand);
  k_rank<<<B_IMG*4, 256, 0, stream>>>(preds, clsA, cand, cnt, cbs_g, obs_g, kmask_g);
  k_iou<<<B_IMG*8, 512, 0, stream>>>(cbs_g, kmask_g, lrows_g);
  k_greedy<<<B_IMG, 512, 0, stream>>>(lrows_g, kmask_g, obs_g, selb, selc);
  k_proj<<<dim3(144, B_IMG), 256, 0, stream>>>(f1, f2, f3, f4, W1, G, P);
  // reduce L2-L4 partial slabs into final G: (294912+73728+18432) f4 / 256
  k_reduce<<<1512, 256, 0, stream>>>((const float4*)P, (float4*)G);
  k_roi_mlp<<<dim3((MAXDET+3)/4, B_IMG), 256, 0, stream>>>(G, selb, selc, b1, W2, b2, out);
}

// Round 6
// 331.336 us; speedup vs baseline: 1.3613x; 1.0818x over previous
//
#include <hip/hip_runtime.h>
#include <cstdint>

#define B_IMG   8
#define NCAND   36720
#define PD      85
#define NCLS    80
#define KC      512
#define MAXDET  300
#define NBUCK   2048
#define CANDCAP 1024      // gathered count is ~512 + one-bucket (<~40): 1024 is safe

// G (fp32, level-major) float offsets: L1[8][9216][64] | L2[8][2304][64] | L3[8][576][64] | L4[8][144][64]
#define G2_OFF 4718592
#define G3_OFF 5898240
#define G4_OFF 6193152
#define G_TOT  6266880

// Partial-sum buffer P (float offsets within P)
#define P2_BASE 0
#define P2_SLAB 1179648
#define P3_BASE 2359296
#define P3_SLAB 294912
#define P4_BASE 3538944
#define P4_SLAB 73728

typedef unsigned int u32;
typedef unsigned long long u64;

__device__ __forceinline__ float leaky(float x){ return x >= 0.f ? x : 0.01f*x; }

__device__ __forceinline__ u64 shfl_u64(u64 v, int lane){
  int lo = __shfl((int)(u32)(v & 0xFFFFFFFFull), lane, 64);
  int hi = __shfl((int)(u32)(v >> 32), lane, 64);
  return ((u64)(u32)hi << 32) | (u64)(u32)lo;
}
__device__ __forceinline__ u64 shfl_xor_u64(u64 v, int mask){
  int lo = __shfl_xor((int)(u32)(v & 0xFFFFFFFFull), mask, 64);
  int hi = __shfl_xor((int)(u32)(v >> 32), mask, 64);
  return ((u64)(u32)hi << 32) | (u64)(u32)lo;
}

// ---------------- K1: two-phase score: obj-filter -> class-scan survivors only ----
__global__ __launch_bounds__(256) void k_score(const float* __restrict__ preds,
    u32* __restrict__ sbits, int* __restrict__ clsArr, u32* __restrict__ hist){
  __shared__ u32   sl_lane[4][64];
  __shared__ float sl_obj[4][64];
  __shared__ u32   sl_res[4][64];
  __shared__ u32   sl_cls[4][64];
  const int img  = blockIdx.y;
  const int wv   = threadIdx.x >> 6;
  const int lane = threadIdx.x & 63;
  const int base = (blockIdx.x*4 + wv)*64;
  const int ci   = base + lane;
  const bool inb = ci < NCAND;
  float obj = 0.f;
  if (inb) obj = preds[((long)img*NCAND + ci)*PD + 4];
  const bool pass = obj > 0.596f;
  u64 mask = __ballot(pass);
  int cnt  = __popcll(mask);
  int rank = __popcll(mask & ((1ull << lane) - 1ull));
  if (pass){ sl_lane[wv][rank] = (u32)lane; sl_obj[wv][rank] = obj; }
  const int q = lane & 3;
  for (int r0 = 0; r0 < cnt; r0 += 16){
    int idx = r0 + (lane >> 2);
    if (idx < cnt){
      u32 sl = sl_lane[wv][idx];
      float obj2 = sl_obj[wv][idx];
      const float* p2 = preds + ((long)img*NCAND + base + (int)sl)*PD + 5 + q;
      u64 best = 0ull;
      #pragma unroll
      for (int k = 0; k < 20; k++){
        float v = p2[4*k] * obj2;                       // exact ref: cls*obj
        u64 key = ((u64)__float_as_uint(v) << 32) | (u64)(~(u32)(q + 4*k));
        if (key > best) best = key;                     // first max wins
      }
      u64 o1 = shfl_xor_u64(best, 1); if (o1 > best) best = o1;
      u64 o2 = shfl_xor_u64(best, 2); if (o2 > best) best = o2;
      if (q == 0){
        u32 bits = (u32)(best >> 32);
        sl_res[wv][sl] = (__uint_as_float(bits) > 0.596f) ? bits : 0u;
        sl_cls[wv][sl] = ~(u32)(best & 0xFFFFFFFFull);
      }
    }
  }
  if (inb){
    u32 out = pass ? sl_res[wv][lane] : 0u;             // valid scores in (0.596,1)
    sbits[(long)img*NCAND + ci] = out;
    if (pass) clsArr[(long)img*NCAND + ci] = (int)sl_cls[wv][lane];
    if (out) atomicAdd(&hist[img*NBUCK + ((out - 0x3F000000u) >> 12)], 1u);
  }
}

// ---------------- K2: per-image bit-threshold covering top-512 ----------------
__global__ __launch_bounds__(64) void k_thresh(const u32* __restrict__ hist,
                                               u32* __restrict__ thr){
  const int img = blockIdx.x;
  const int lane = threadIdx.x;
  const u32* h = hist + img*NBUCK;
  u32 acc = 0; u32 result = 0x3F000000u; bool found = false;
  for (int g = NBUCK/64 - 1; g >= 0 && !found; g--){
    u32 v = h[g*64 + lane];
    u32 s = v;
    #pragma unroll
    for (int off = 1; off < 64; off <<= 1){
      u32 t = __shfl_down(s, off, 64);
      s += (lane + off < 64) ? t : 0u;
    }
    u64 mask = __ballot(acc + s >= KC);
    if (mask){
      int hl = 63 - __clzll(mask);
      result = 0x3F000000u + ((u32)(g*64 + hl) << 12);
      found = true;
    }
    acc += __shfl(s, 0, 64);
  }
  if (lane == 0) thr[img] = result;
}

// ---------------- K3: gather candidates >= threshold as sortable keys ----------------
__global__ __launch_bounds__(256) void k_gather(const u32* __restrict__ sbits,
    const u32* __restrict__ thr, u32* __restrict__ cnt, u64* __restrict__ cand){
  int img = blockIdx.y;
  int n = blockIdx.x*256 + threadIdx.x;
  if (n >= NCAND) return;
  u32 bits = sbits[(long)img*NCAND + n];
  if (bits && bits >= thr[img]){
    u32 pos = atomicAdd(&cnt[img], 1u);
    if (pos < CANDCAP)
      cand[(long)img*CANDCAP + pos] = ((u64)bits << 32) | (u64)(0xFFFFFFFFu - (u32)n);
  }
}

// ---------------- K4a: rank + decode ranked boxes to global ----------------
__global__ __launch_bounds__(256) void k_rank(const float* __restrict__ preds,
    const int* __restrict__ clsArr, const u64* __restrict__ cand,
    const u32* __restrict__ cnt, float4* __restrict__ cbs_g,
    float4* __restrict__ obs_g, u64* __restrict__ kmask_g){
#pragma clang fp contract(off)
  __shared__ __align__(16) u64 keys[CANDCAP];      // 8 KB
  const int img = blockIdx.x >> 2;
  const int sub = blockIdx.x & 3;
  const int tid = threadIdx.x;
  const int M = min((int)cnt[img], CANDCAP);
  #pragma unroll
  for (int k = 0; k < 4; k++){
    int s = k*256 + tid;
    keys[s] = (s < M) ? cand[(long)img*CANDCAP + s] : 0ull;
  }
  __syncthreads();
  const int slot = sub*256 + tid;
  u64 k0 = keys[slot];
  int r0 = 0;
  const ulonglong2* kv = (const ulonglong2*)keys;
  for (int j = 0; j < CANDCAP/2; j++){              // wave-uniform b128 broadcast
    ulonglong2 kk = kv[j];
    r0 += (kk.x > k0) + (kk.y > k0);
  }
  if ((k0 >> 32) != 0ull && r0 < KC){
    u32 idxn = 0xFFFFFFFFu - (u32)(k0 & 0xFFFFFFFFull);
    const float* p = preds + ((long)img*NCAND + idxn)*PD;
    float cx = p[0], cy = p[1], w = p[2], h = p[3];
    float hw = w*0.5f, hh = h*0.5f;                 // exact
    float X1 = cx-hw, Y1 = cy-hh, X2 = cx+hw, Y2 = cy+hh;
    float off = (float)clsArr[(long)img*NCAND + idxn] * 4096.0f;  // exact
    obs_g[(long)img*KC + r0] = make_float4(X1, Y1, X2, Y2);
    cbs_g[(long)img*KC + r0] = make_float4(X1+off, Y1+off, X2+off, Y2+off);
    atomicOr(&kmask_g[img*8 + (r0 >> 6)], 1ull << (r0 & 63));
  }
}

// ---------------- K4b: IOU suppression matrix, 64 rows x 512 cols per block ----
__global__ __launch_bounds__(512) void k_iou(const float4* __restrict__ cbs_g,
    const u64* __restrict__ kmask_g, u64* __restrict__ lrows_g){
#pragma clang fp contract(off)
  __shared__ __align__(16) float4 cbsL[8*65];      // stride-65 swizzle: conflict-free
  const int img = blockIdx.x >> 3;
  const int ch  = blockIdx.x & 7;
  const int tid = threadIdx.x;
  if (tid < KC){
    u64 km = kmask_g[img*8 + (tid >> 6)];
    bool f = (km >> (tid & 63)) & 1ull;
    float4 v = f ? cbs_g[(long)img*KC + tid]
                 : make_float4(-4e8f, -4e8f, -4e8f, -4e8f);  // zero-area -> iou 0
    cbsL[(tid >> 6)*65 + (tid & 63)] = v;
  }
  __syncthreads();
  const int row = ch*64 + (tid >> 3);
  const int w   = tid & 7;
  float4 bi = cbsL[(row >> 6)*65 + (row & 63)];
  float areai = (bi.z - bi.x)*(bi.w - bi.y);
  u64 bits = 0ull;
  const int jbase = w*64;
  for (int b = 0; b < 64; b++){
    int j = jbase + b;
    if (j > row){
      float4 bj = cbsL[w*65 + b];
      float areaj = (bj.z - bj.x)*(bj.w - bj.y);
      float ltx = fmaxf(bi.x, bj.x), lty = fmaxf(bi.y, bj.y);
      float rbx = fminf(bi.z, bj.z), rby = fminf(bi.w, bj.w);
      float ww = fmaxf(rbx - ltx, 0.f);
      float hh = fmaxf(rby - lty, 0.f);
      float inter = ww*hh;
      float iou = inter / (areai + areaj - inter + 1e-7f);  // exact ref op order
      if (iou > 0.45f) bits |= (1ull << b);
    }
  }
  lrows_g[((long)img*KC + row)*8 + w] = bits;      // coalesced 8B stores
}

// ---------------- K4c: greedy suppression (serial core) + compact ----------------
__global__ __launch_bounds__(512) void k_greedy(const u64* __restrict__ lrows_g,
    const u64* __restrict__ kmask_g, const float4* __restrict__ obs_g,
    float* __restrict__ selbox, u32* __restrict__ selcnt){
  __shared__ __align__(16) u64 lrows[KC*8];        // 32 KB
  __shared__ u64 keepw[8];
  const int img = blockIdx.x;
  const int tid = threadIdx.x;
  const ulonglong2* src = (const ulonglong2*)(lrows_g + (long)img*KC*8);
  ulonglong2* dst = (ulonglong2*)lrows;
  #pragma unroll
  for (int k = 0; k < 4; k++) dst[k*512 + tid] = src[k*512 + tid];
  __syncthreads();
  if (tid < 64){
    const int lane = tid;
    const int w = lane & 7;
    u64 kw_own = kmask_g[img*8 + w];
    for (int b = 0; b < 8; b++){
      u64 kwb = shfl_u64(kw_own, b);
      for (int g = 0; g < 8; g++){
        u64 rdec[8], rown[8];
        #pragma unroll
        for (int k = 0; k < 8; k++){
          int i = b*64 + g*8 + k;
          rdec[k] = lrows[i*8 + b];
          rown[k] = lrows[i*8 + w];
        }
        #pragma unroll
        for (int k = 0; k < 8; k++){
          int il = g*8 + k;
          if ((kwb >> il) & 1ull){
            kwb    &= ~rdec[k];
            kw_own &= ~rown[k];
          }
        }
      }
    }
    if (lane < 8) keepw[lane] = kw_own;
  }
  __syncthreads();
  {
    u64 kk[8];
    #pragma unroll
    for (int w = 0; w < 8; w++) kk[w] = keepw[w];
    const int s = tid;
    const int wi = s >> 6, bi = s & 63;
    bool kept = (kk[wi] >> bi) & 1ull;
    if (kept){
      int rank = 0;
      for (int w = 0; w < wi; w++) rank += __popcll(kk[w]);
      rank += __popcll(bi ? (kk[wi] & ((1ull << bi) - 1ull)) : 0ull);
      if (rank < MAXDET){
        float4 ob = obs_g[(long)img*KC + s];
        float* sb = selbox + ((long)img*MAXDET + rank)*4;
        sb[0]=ob.x; sb[1]=ob.y; sb[2]=ob.z; sb[3]=ob.w;
      }
    }
    if (tid == 0){
      int tot = 0;
      #pragma unroll
      for (int w = 0; w < 8; w++) tot += __popcll(kk[w]);
      selcnt[img] = (u32)min(tot, MAXDET);
    }
  }
}

// ---------------- K5: projection GEMM, split-K balanced, async LDS staging ----
// R13: R10-R12's register-prefetch (rF[4]/rW[2] live across the 32-iter FMA
// loop) SPILLED TO SCRATCH: VGPR_Count=44 < 56 live values, WRITE_SIZE 131MB
// = 35MB useful + ~96MB scratch stores (R0 without prefetch wrote exactly its
// G footprint; the excess appeared the round the prefetch was added). The
// "prefetch" was a store/reload through HBM-backed scratch. Fix: no staging
// registers at all -- __builtin_amdgcn_global_load_lds (16B) DMAs global->LDS
// directly into a DOUBLE-BUFFERED tile; one __syncthreads per chunk drains
// vmcnt. Load latency (~900cy) hides under the 2048cy FMA loop. LDS 48KB ->
// 3 blocks/CU (same occupancy as before). FMA loop + stores unchanged ->
// bit-identical output.
__device__ __forceinline__ void gld16(const void* g, void* l){
  __builtin_amdgcn_global_load_lds((const __attribute__((address_space(1))) void*)g,
                                   (__attribute__((address_space(3))) void*)l, 16, 0, 0);
}

__device__ __forceinline__ void stage_chunk(const float4* __restrict__ feat4,
    const float4* __restrict__ W14, long fbase, int hw4, int px04, int Woff,
    int c0, int tid, float4* FsD, float4* WsD){
  const int wb = tid & ~63;                      // wave-uniform LDS base
  #pragma unroll
  for (int k = 0; k < 4; k++){
    int s = tid + k*256; int c = s >> 5, q = s & 31;
    int pq = px04 + q; if (pq >= hw4) pq = hw4 - 1;   // ragged tile clamp (stores guarded)
    gld16(feat4 + fbase + (long)(c0 + c)*hw4 + pq, FsD + k*256 + wb);
  }
  #pragma unroll
  for (int k = 0; k < 2; k++){
    int s = tid + k*256; int c = s >> 4, q = s & 15;
    gld16(W14 + (long)(Woff + c0 + c)*16 + q, WsD + k*256 + wb);
  }
}

#define FMA_ROW(S, A) \
  A.x = fmaf(S, wv.x, A.x); A.y = fmaf(S, wv.y, A.y); \
  A.z = fmaf(S, wv.z, A.z); A.w = fmaf(S, wv.w, A.w);

__global__ __launch_bounds__(256) void k_proj(const float* __restrict__ f1,
    const float* __restrict__ f2, const float* __restrict__ f3,
    const float* __restrict__ f4, const float* __restrict__ W1,
    float* __restrict__ G, float* __restrict__ P){
  __shared__ __align__(16) float Fs[2][32*128];  // 32 KB (double-buffered)
  __shared__ __align__(16) float Ws[2][32*64];   // 16 KB
  const int img = blockIdx.y;
  const int u   = blockIdx.x;                  // 144 blocks/img, all equal work
  const float* feat; int C, HW, Woff, tile, split; long pbase; bool multi;
  if (u < 16)      { feat=f4; C=1024; HW=144;  Woff=896; tile=u>>3;      split=u&7;
                     pbase=P4_BASE + (long)split*P4_SLAB; multi=true;  }
  else if (u < 36) { feat=f3; C=512;  HW=576;  Woff=384; tile=(u-16)>>2; split=(u-16)&3;
                     pbase=P3_BASE + (long)split*P3_SLAB; multi=true;  }
  else if (u < 72) { feat=f2; C=256;  HW=2304; Woff=128; tile=(u-36)>>1; split=(u-36)&1;
                     pbase=P2_BASE + (long)split*P2_SLAB; multi=true;  }
  else             { feat=f1; C=128;  HW=9216; Woff=0;   tile=u-72;      split=0;
                     pbase=0; multi=false; }
  const int px0  = tile*128;
  const int hw4  = HW >> 2;
  const int px04 = px0 >> 2;
  const int tid  = threadIdx.x;
  const int jg   = tid & 15;        // j group: j = jg*4..jg*4+3  (lane-fast axis)
  const int pg   = tid >> 4;        // px group: px = px0 + pg*8 + p, p=0..7
  const int c0b  = split*128;
  const float4* feat4 = (const float4*)feat;
  const float4* W14   = (const float4*)W1;
  const long fbase = (long)img*C*hw4;
  float4 a0 = make_float4(0.f,0.f,0.f,0.f), a1 = a0, a2 = a0, a3 = a0;
  float4 a4 = a0, a5 = a0, a6 = a0, a7 = a0;

  stage_chunk(feat4, W14, fbase, hw4, px04, Woff, c0b, tid,
              (float4*)Fs[0], (float4*)Ws[0]);
  __syncthreads();                               // drains vmcnt: buf0 ready
  for (int ch = 0; ch < 4; ch++){
    if (ch < 3)                                  // issue next chunk into buf^1
      stage_chunk(feat4, W14, fbase, hw4, px04, Woff, c0b + (ch+1)*32, tid,
                  (float4*)Fs[(ch+1)&1], (float4*)Ws[(ch+1)&1]);
    const float4* fsb = (const float4*)Fs[ch&1];
    const float4* wsb = (const float4*)Ws[ch&1];
    #pragma unroll 8
    for (int c = 0; c < 32; c++){
      float4 fa = fsb[c*32 + pg*2];        // px pg*8..pg*8+3 (16-lane broadcast)
      float4 fb = fsb[c*32 + pg*2 + 1];    // px pg*8+4..pg*8+7
      float4 wv = wsb[c*16 + jg];          // j jg*4..jg*4+3 (2-way aliased: free)
      FMA_ROW(fa.x, a0) FMA_ROW(fa.y, a1) FMA_ROW(fa.z, a2) FMA_ROW(fa.w, a3)
      FMA_ROW(fb.x, a4) FMA_ROW(fb.y, a5) FMA_ROW(fb.z, a6) FMA_ROW(fb.w, a7)
    }
    __syncthreads();                             // drains next-chunk loads + compute done
  }
  float* outb = multi ? (P + pbase + (long)img*HW*64)
                      : (G + (long)img*HW*64);           // L1 region starts at G+0
  const int pxa = px0 + pg*8;
#define STOREQ(A, PP) do { int gp = pxa + (PP); if (gp < HW){ \
    *(float4*)(outb + (long)gp*64 + jg*4) = A; } } while(0)
  STOREQ(a0, 0); STOREQ(a1, 1); STOREQ(a2, 2); STOREQ(a3, 3);
  STOREQ(a4, 4); STOREQ(a5, 5); STOREQ(a6, 6); STOREQ(a7, 7);
#undef STOREQ
}

// ---------------- K5b: sum split-K partial slabs into final G (L2-L4 region) ----
__global__ __launch_bounds__(256) void k_reduce(const float4* __restrict__ P4f,
                                                float4* __restrict__ G4f){
  const int N2 = P2_SLAB/4;   // 294912 f4
  const int N3 = P3_SLAB/4;   // 73728  f4
  const int N4 = P4_SLAB/4;   // 18432  f4
  int t = blockIdx.x*256 + threadIdx.x;
  if (t < N2){
    float4 a = P4f[t];
    float4 b = P4f[N2 + t];
    float4 r = make_float4(a.x+b.x, a.y+b.y, a.z+b.z, a.w+b.w);
    G4f[G2_OFF/4 + t] = r;
  } else if (t < N2 + N3){
    int u = t - N2;
    const float4* base = P4f + P3_BASE/4 + u;
    float4 r = base[0];
    #pragma unroll
    for (int s = 1; s < 4; s++){
      float4 b = base[(long)s*N3];
      r.x += b.x; r.y += b.y; r.z += b.z; r.w += b.w;
    }
    G4f[G3_OFF/4 + u] = r;
  } else if (t < N2 + N3 + N4){
    int u = t - N2 - N3;
    const float4* base = P4f + P4_BASE/4 + u;
    float4 r = base[0];
    #pragma unroll
    for (int s = 1; s < 8; s++){
      float4 b = base[(long)s*N4];
      r.x += b.x; r.y += b.y; r.z += b.z; r.w += b.w;
    }
    G4f[G4_OFF/4 + u] = r;
  }
}

// ---------------- K6: fused ROI-gather + bias + leaky + layer2 + assembly ----------------
__device__ __forceinline__ void roi_level(const float* __restrict__ g,
    int Hl, int Wl, float scale, float x1, float y1, float x2, float y2,
    int lane, float& h){
  float bx1=x1*scale, by1=y1*scale, bx2=x2*scale, by2=y2*scale;
  float rw=fmaxf(bx2-bx1,1.f), rh=fmaxf(by2-by1,1.f);
  float ys[2]={by1+rh*0.25f, by1+rh*0.75f};
  float xs[2]={bx1+rw*0.25f, bx1+rw*0.75f};
  #pragma unroll
  for (int pt = 0; pt < 4; pt++){
    float y=ys[pt>>1], x=xs[pt&1];
    if ((y>-1.f)&&(y<(float)Hl)&&(x>-1.f)&&(x<(float)Wl)){   // wave-uniform branch
      float yc=fmaxf(y,0.f), xc=fmaxf(x,0.f);
      int y0=(int)fminf(floorf(yc),(float)(Hl-1));
      int x0=(int)fminf(floorf(xc),(float)(Wl-1));
      int y1i=min(y0+1,Hl-1), x1i=min(x0+1,Wl-1);
      float ly=yc-(float)y0, lx=xc-(float)x0;
      float hy=1.f-ly, hx=1.f-lx;
      h += (hy*hx*0.25f)*g[(long)(y0*Wl+x0)*64+lane];
      h += (hy*lx*0.25f)*g[(long)(y0*Wl+x1i)*64+lane];
      h += (ly*hx*0.25f)*g[(long)(y1i*Wl+x0)*64+lane];
      h += (ly*lx*0.25f)*g[(long)(y1i*Wl+x1i)*64+lane];
    }
  }
}

__global__ __launch_bounds__(256) void k_roi_mlp(const float* __restrict__ G,
    const float* __restrict__ selbox, const u32* __restrict__ selcnt,
    const float* __restrict__ b1, const float* __restrict__ W2,
    const float* __restrict__ b2, float* __restrict__ out){
  const int img  = blockIdx.y;
  const int wave = threadIdx.x >> 6;
  const int lane = threadIdx.x & 63;
  const int slot = blockIdx.x*4 + wave;
  if (slot >= MAXDET) return;
  float* o = out + ((long)img*MAXDET + slot)*68;
  if (slot >= (int)selcnt[img]){
    o[4+lane] = 0.f;
    if (lane < 4) o[lane] = 0.f;
    return;
  }
  const float* sb = selbox + ((long)img*MAXDET + slot)*4;
  float x1 = sb[0], y1 = sb[1], x2 = sb[2], y2 = sb[3];
  const float* Gi1 = G +          (long)img*9216*64;
  const float* Gi2 = G + G2_OFF + (long)img*2304*64;
  const float* Gi3 = G + G3_OFF + (long)img*576*64;
  const float* Gi4 = G + G4_OFF + (long)img*144*64;
  float h = 0.f;
  roi_level(Gi1, 96, 96, 0.125f,    x1,y1,x2,y2, lane, h);
  roi_level(Gi2, 48, 48, 0.0625f,   x1,y1,x2,y2, lane, h);
  roi_level(Gi3, 24, 24, 0.03125f,  x1,y1,x2,y2, lane, h);
  roi_level(Gi4, 12, 12, 0.015625f, x1,y1,x2,y2, lane, h);
  float h1 = leaky(h + b1[lane]);
  float c = 0.f;
  #pragma unroll 8
  for (int k = 0; k < 64; k++){
    float hk = __shfl(h1, k, 64);
    c += hk * W2[k*64 + lane];
  }
  o[4+lane] = leaky(c + b2[lane]);
  if (lane < 4) o[lane] = sb[lane] / 768.0f;
}

// ---------------- workspace layout (bytes) ----------------
// 0        hist    u32[8][2048]        65536
// 65536    cnt     u32[8]              256 (padded)
// 65792    kmask   u64[8][8]           512
// 66304    thr     u32[8]              256
// 66560    selbox  f32[8][300][4]      38400
// 104960   selcnt  u32[8]              256
// 105216   sbits   u32[8][36720]       1175040
// 1280256  cls     i32[8][36720]       1175040
// 2455296  cand    u64[8][1024]        65536
// 2520832  cbs_g   f4[8][512]          65536
// 2586368  obs_g   f4[8][512]          65536
// 2651904  lrows_g u64[8][512][8]      262144
// 2914048  G       f32 level-major     25067520
// 27981568 P       f32 partials        16515072   -> total ~44.5 MB
#define WS_G 2914048
#define WS_P 27981568

extern "C" void kernel_launch(void* const* d_in, const int* in_sizes, int n_in,
                              void* d_out, int out_size, void* d_ws, size_t ws_size,
                              hipStream_t stream){
  const float* preds = (const float*)d_in[0];
  const float* f1 = (const float*)d_in[1];
  const float* f2 = (const float*)d_in[2];
  const float* f3 = (const float*)d_in[3];
  const float* f4 = (const float*)d_in[4];
  const float* W1 = (const float*)d_in[5];
  const float* b1 = (const float*)d_in[6];
  const float* W2 = (const float*)d_in[7];
  const float* b2 = (const float*)d_in[8];
  float* out = (float*)d_out;
  char* ws = (char*)d_ws;
  u32* hist    = (u32*)(ws + 0);
  u32* cnt     = (u32*)(ws + 65536);
  u64* kmask_g = (u64*)(ws + 65792);
  u32* thr     = (u32*)(ws + 66304);
  float* selb  = (float*)(ws + 66560);
  u32* selc    = (u32*)(ws + 104960);
  u32* sbits   = (u32*)(ws + 105216);
  int* clsA    = (int*)(ws + 1280256);
  u64* cand    = (u64*)(ws + 2455296);
  float4* cbs_g = (float4*)(ws + 2520832);
  float4* obs_g = (float4*)(ws + 2586368);
  u64* lrows_g  = (u64*)(ws + 2651904);
  float* G     = (float*)(ws + WS_G);
  float* P     = (float*)(ws + WS_P);

  hipMemsetAsync(ws, 0, 66304, stream);                 // hist + cnt + kmask

  dim3 gs((NCAND + 255)/256, B_IMG);
  k_score<<<gs, 256, 0, stream>>>(preds, sbits, clsA, hist);
  k_thresh<<<B_IMG, 64, 0, stream>>>(hist, thr);
  dim3 g3((NCAND+255)/256, B_IMG);
  k_gather<<<g3, 256, 0, stream>>>(sbits, thr, cnt, cand);
  k_rank<<<B_IMG*4, 256, 0, stream>>>(preds, clsA, cand, cnt, cbs_g, obs_g, kmask_g);
  k_iou<<<B_IMG*8, 512, 0, stream>>>(cbs_g, kmask_g, lrows_g);
  k_greedy<<<B_IMG, 512, 0, stream>>>(lrows_g, kmask_g, obs_g, selb, selc);
  k_proj<<<dim3(144, B_IMG), 256, 0, stream>>>(f1, f2, f3, f4, W1, G, P);
  // reduce L2-L4 partial slabs into final G: (294912+73728+18432) f4 / 256
  k_reduce<<<1512, 256, 0, stream>>>((const float4*)P, (float4*)G);
  k_roi_mlp<<<dim3((MAXDET+3)/4, B_IMG), 256, 0, stream>>>(G, selb, selc, b1, W2, b2, out);
}

// Round 7
// 327.921 us; speedup vs baseline: 1.3755x; 1.0104x over previous
//
#include <hip/hip_runtime.h>
#include <cstdint>

#define B_IMG   8
#define NCAND   36720
#define PD      85
#define NCLS    80
#define KC      512
#define MAXDET  300
#define NBUCK   2048
#define CANDCAP 1024      // gathered count is ~512 + one-bucket (<~40): 1024 is safe

// G (fp32, level-major) float offsets: L1[8][9216][64] | L2[8][2304][64] | L3[8][576][64] | L4[8][144][64]
#define G2_OFF 4718592
#define G3_OFF 5898240
#define G4_OFF 6193152
#define G_TOT  6266880

// Partial-sum buffer P (float offsets within P)
#define P2_BASE 0
#define P2_SLAB 1179648
#define P3_BASE 2359296
#define P3_SLAB 294912
#define P4_BASE 3538944
#define P4_SLAB 73728

typedef unsigned int u32;
typedef unsigned long long u64;

__device__ __forceinline__ float leaky(float x){ return x >= 0.f ? x : 0.01f*x; }

__device__ __forceinline__ u64 shfl_u64(u64 v, int lane){
  int lo = __shfl((int)(u32)(v & 0xFFFFFFFFull), lane, 64);
  int hi = __shfl((int)(u32)(v >> 32), lane, 64);
  return ((u64)(u32)hi << 32) | (u64)(u32)lo;
}
__device__ __forceinline__ u64 shfl_xor_u64(u64 v, int mask){
  int lo = __shfl_xor((int)(u32)(v & 0xFFFFFFFFull), mask, 64);
  int hi = __shfl_xor((int)(u32)(v >> 32), mask, 64);
  return ((u64)(u32)hi << 32) | (u64)(u32)lo;
}

// ---------------- K1: two-phase score: obj-filter -> class-scan survivors only ----
__global__ __launch_bounds__(256) void k_score(const float* __restrict__ preds,
    u32* __restrict__ sbits, int* __restrict__ clsArr, u32* __restrict__ hist){
  __shared__ u32   sl_lane[4][64];
  __shared__ float sl_obj[4][64];
  __shared__ u32   sl_res[4][64];
  __shared__ u32   sl_cls[4][64];
  const int img  = blockIdx.y;
  const int wv   = threadIdx.x >> 6;
  const int lane = threadIdx.x & 63;
  const int base = (blockIdx.x*4 + wv)*64;
  const int ci   = base + lane;
  const bool inb = ci < NCAND;
  float obj = 0.f;
  if (inb) obj = preds[((long)img*NCAND + ci)*PD + 4];
  const bool pass = obj > 0.596f;
  u64 mask = __ballot(pass);
  int cnt  = __popcll(mask);
  int rank = __popcll(mask & ((1ull << lane) - 1ull));
  if (pass){ sl_lane[wv][rank] = (u32)lane; sl_obj[wv][rank] = obj; }
  const int q = lane & 3;
  for (int r0 = 0; r0 < cnt; r0 += 16){
    int idx = r0 + (lane >> 2);
    if (idx < cnt){
      u32 sl = sl_lane[wv][idx];
      float obj2 = sl_obj[wv][idx];
      const float* p2 = preds + ((long)img*NCAND + base + (int)sl)*PD + 5 + q;
      u64 best = 0ull;
      #pragma unroll
      for (int k = 0; k < 20; k++){
        float v = p2[4*k] * obj2;                       // exact ref: cls*obj
        u64 key = ((u64)__float_as_uint(v) << 32) | (u64)(~(u32)(q + 4*k));
        if (key > best) best = key;                     // first max wins
      }
      u64 o1 = shfl_xor_u64(best, 1); if (o1 > best) best = o1;
      u64 o2 = shfl_xor_u64(best, 2); if (o2 > best) best = o2;
      if (q == 0){
        u32 bits = (u32)(best >> 32);
        sl_res[wv][sl] = (__uint_as_float(bits) > 0.596f) ? bits : 0u;
        sl_cls[wv][sl] = ~(u32)(best & 0xFFFFFFFFull);
      }
    }
  }
  if (inb){
    u32 out = pass ? sl_res[wv][lane] : 0u;             // valid scores in (0.596,1)
    sbits[(long)img*NCAND + ci] = out;
    if (pass) clsArr[(long)img*NCAND + ci] = (int)sl_cls[wv][lane];
    if (out) atomicAdd(&hist[img*NBUCK + ((out - 0x3F000000u) >> 12)], 1u);
  }
}

// ---------------- K2: per-image bit-threshold covering top-512 ----------------
__global__ __launch_bounds__(64) void k_thresh(const u32* __restrict__ hist,
                                               u32* __restrict__ thr){
  const int img = blockIdx.x;
  const int lane = threadIdx.x;
  const u32* h = hist + img*NBUCK;
  u32 acc = 0; u32 result = 0x3F000000u; bool found = false;
  for (int g = NBUCK/64 - 1; g >= 0 && !found; g--){
    u32 v = h[g*64 + lane];
    u32 s = v;
    #pragma unroll
    for (int off = 1; off < 64; off <<= 1){
      u32 t = __shfl_down(s, off, 64);
      s += (lane + off < 64) ? t : 0u;
    }
    u64 mask = __ballot(acc + s >= KC);
    if (mask){
      int hl = 63 - __clzll(mask);
      result = 0x3F000000u + ((u32)(g*64 + hl) << 12);
      found = true;
    }
    acc += __shfl(s, 0, 64);
  }
  if (lane == 0) thr[img] = result;
}

// ---------------- K3: gather candidates >= threshold as sortable keys ----------------
__global__ __launch_bounds__(256) void k_gather(const u32* __restrict__ sbits,
    const u32* __restrict__ thr, u32* __restrict__ cnt, u64* __restrict__ cand){
  int img = blockIdx.y;
  int n = blockIdx.x*256 + threadIdx.x;
  if (n >= NCAND) return;
  u32 bits = sbits[(long)img*NCAND + n];
  if (bits && bits >= thr[img]){
    u32 pos = atomicAdd(&cnt[img], 1u);
    if (pos < CANDCAP)
      cand[(long)img*CANDCAP + pos] = ((u64)bits << 32) | (u64)(0xFFFFFFFFu - (u32)n);
  }
}

// ---------------- K4a: rank + decode ranked boxes to global ----------------
__global__ __launch_bounds__(256) void k_rank(const float* __restrict__ preds,
    const int* __restrict__ clsArr, const u64* __restrict__ cand,
    const u32* __restrict__ cnt, float4* __restrict__ cbs_g,
    float4* __restrict__ obs_g, u64* __restrict__ kmask_g){
#pragma clang fp contract(off)
  __shared__ __align__(16) u64 keys[CANDCAP];      // 8 KB
  const int img = blockIdx.x >> 2;
  const int sub = blockIdx.x & 3;
  const int tid = threadIdx.x;
  const int M = min((int)cnt[img], CANDCAP);
  #pragma unroll
  for (int k = 0; k < 4; k++){
    int s = k*256 + tid;
    keys[s] = (s < M) ? cand[(long)img*CANDCAP + s] : 0ull;
  }
  __syncthreads();
  const int slot = sub*256 + tid;
  u64 k0 = keys[slot];
  int r0 = 0;
  const ulonglong2* kv = (const ulonglong2*)keys;
  for (int j = 0; j < CANDCAP/2; j++){              // wave-uniform b128 broadcast
    ulonglong2 kk = kv[j];
    r0 += (kk.x > k0) + (kk.y > k0);
  }
  if ((k0 >> 32) != 0ull && r0 < KC){
    u32 idxn = 0xFFFFFFFFu - (u32)(k0 & 0xFFFFFFFFull);
    const float* p = preds + ((long)img*NCAND + idxn)*PD;
    float cx = p[0], cy = p[1], w = p[2], h = p[3];
    float hw = w*0.5f, hh = h*0.5f;                 // exact
    float X1 = cx-hw, Y1 = cy-hh, X2 = cx+hw, Y2 = cy+hh;
    float off = (float)clsArr[(long)img*NCAND + idxn] * 4096.0f;  // exact
    obs_g[(long)img*KC + r0] = make_float4(X1, Y1, X2, Y2);
    cbs_g[(long)img*KC + r0] = make_float4(X1+off, Y1+off, X2+off, Y2+off);
    atomicOr(&kmask_g[img*8 + (r0 >> 6)], 1ull << (r0 & 63));
  }
}

// ---------------- K4b: IOU suppression matrix, 64 rows x 512 cols per block ----
__global__ __launch_bounds__(512) void k_iou(const float4* __restrict__ cbs_g,
    const u64* __restrict__ kmask_g, u64* __restrict__ lrows_g){
#pragma clang fp contract(off)
  __shared__ __align__(16) float4 cbsL[8*65];      // stride-65 swizzle: conflict-free
  const int img = blockIdx.x >> 3;
  const int ch  = blockIdx.x & 7;
  const int tid = threadIdx.x;
  if (tid < KC){
    u64 km = kmask_g[img*8 + (tid >> 6)];
    bool f = (km >> (tid & 63)) & 1ull;
    float4 v = f ? cbs_g[(long)img*KC + tid]
                 : make_float4(-4e8f, -4e8f, -4e8f, -4e8f);  // zero-area -> iou 0
    cbsL[(tid >> 6)*65 + (tid & 63)] = v;
  }
  __syncthreads();
  const int row = ch*64 + (tid >> 3);
  const int w   = tid & 7;
  float4 bi = cbsL[(row >> 6)*65 + (row & 63)];
  float areai = (bi.z - bi.x)*(bi.w - bi.y);
  u64 bits = 0ull;
  const int jbase = w*64;
  for (int b = 0; b < 64; b++){
    int j = jbase + b;
    if (j > row){
      float4 bj = cbsL[w*65 + b];
      float areaj = (bj.z - bj.x)*(bj.w - bj.y);
      float ltx = fmaxf(bi.x, bj.x), lty = fmaxf(bi.y, bj.y);
      float rbx = fminf(bi.z, bj.z), rby = fminf(bi.w, bj.w);
      float ww = fmaxf(rbx - ltx, 0.f);
      float hh = fmaxf(rby - lty, 0.f);
      float inter = ww*hh;
      float iou = inter / (areai + areaj - inter + 1e-7f);  // exact ref op order
      if (iou > 0.45f) bits |= (1ull << b);
    }
  }
  lrows_g[((long)img*KC + row)*8 + w] = bits;      // coalesced 8B stores
}

// ---------------- K4c: greedy suppression (serial core) + compact ----------------
__global__ __launch_bounds__(512) void k_greedy(const u64* __restrict__ lrows_g,
    const u64* __restrict__ kmask_g, const float4* __restrict__ obs_g,
    float* __restrict__ selbox, u32* __restrict__ selcnt){
  __shared__ __align__(16) u64 lrows[KC*8];        // 32 KB
  __shared__ u64 keepw[8];
  const int img = blockIdx.x;
  const int tid = threadIdx.x;
  const ulonglong2* src = (const ulonglong2*)(lrows_g + (long)img*KC*8);
  ulonglong2* dst = (ulonglong2*)lrows;
  #pragma unroll
  for (int k = 0; k < 4; k++) dst[k*512 + tid] = src[k*512 + tid];
  __syncthreads();
  if (tid < 64){
    const int lane = tid;
    const int w = lane & 7;
    u64 kw_own = kmask_g[img*8 + w];
    for (int b = 0; b < 8; b++){
      u64 kwb = shfl_u64(kw_own, b);
      for (int g = 0; g < 8; g++){
        u64 rdec[8], rown[8];
        #pragma unroll
        for (int k = 0; k < 8; k++){
          int i = b*64 + g*8 + k;
          rdec[k] = lrows[i*8 + b];
          rown[k] = lrows[i*8 + w];
        }
        #pragma unroll
        for (int k = 0; k < 8; k++){
          int il = g*8 + k;
          if ((kwb >> il) & 1ull){
            kwb    &= ~rdec[k];
            kw_own &= ~rown[k];
          }
        }
      }
    }
    if (lane < 8) keepw[lane] = kw_own;
  }
  __syncthreads();
  {
    u64 kk[8];
    #pragma unroll
    for (int w = 0; w < 8; w++) kk[w] = keepw[w];
    const int s = tid;
    const int wi = s >> 6, bi = s & 63;
    bool kept = (kk[wi] >> bi) & 1ull;
    if (kept){
      int rank = 0;
      for (int w = 0; w < wi; w++) rank += __popcll(kk[w]);
      rank += __popcll(bi ? (kk[wi] & ((1ull << bi) - 1ull)) : 0ull);
      if (rank < MAXDET){
        float4 ob = obs_g[(long)img*KC + s];
        float* sb = selbox + ((long)img*MAXDET + rank)*4;
        sb[0]=ob.x; sb[1]=ob.y; sb[2]=ob.z; sb[3]=ob.w;
      }
    }
    if (tid == 0){
      int tot = 0;
      #pragma unroll
      for (int w = 0; w < 8; w++) tot += __popcll(kk[w]);
      selcnt[img] = (u32)min(tot, MAXDET);
    }
  }
}

// ---------------- K5: projection GEMM: 8px x 8j micro-tile, 16-ch chunks ----
// R14: with scratch fixed (R13: WRITE 131->34.5MB), k_proj is LDS-pipe bound:
// 3 ds_read_b128 per 32 FMA = 1.77M ds-instr chip-wide (~29us floor on the
// per-CU LDS port) + 48KB LDS capped 3 blocks/CU (17.6% occ) -> 70us.
// Now: thread = 8px x 8j (64 FMA per 4 ds_read = 16 FMA/read, -33% ds-instr),
// block = 128 threads (16 pg x 8 jg), chunk = 16 channels double-buffered:
// LDS 24KB -> 6 blocks/CU (12 waves, 37.5% occ). Same 128px x 128ch tile,
// same c-ascending FMA order, same stores -> bit-identical. Staging stays
// global_load_lds (no spillable registers).
__device__ __forceinline__ void gld16(const void* g, void* l){
  __builtin_amdgcn_global_load_lds((const __attribute__((address_space(1))) void*)g,
                                   (__attribute__((address_space(3))) void*)l, 16, 0, 0);
}

__device__ __forceinline__ void stage_chunk(const float4* __restrict__ feat4,
    const float4* __restrict__ W14, long fbase, int hw4, int px04, int Woff,
    int c0, int tid, float4* FsD, float4* WsD){
  const int wb = tid & ~63;                      // wave-uniform LDS base
  #pragma unroll
  for (int k = 0; k < 4; k++){                   // Fs: 16c x 32 f4 = 512 slots
    int s = tid + k*128; int c = s >> 5, q = s & 31;
    int pq = px04 + q; if (pq >= hw4) pq = hw4 - 1;   // ragged tile clamp (stores guarded)
    gld16(feat4 + fbase + (long)(c0 + c)*hw4 + pq, FsD + k*128 + wb);
  }
  #pragma unroll
  for (int k = 0; k < 2; k++){                   // Ws: 16c x 16 f4 = 256 slots
    int s = tid + k*128; int c = s >> 4, q = s & 15;
    gld16(W14 + (long)(Woff + c0 + c)*16 + q, WsD + k*128 + wb);
  }
}

#define FMA_Q(S, W, A) \
  A.x = fmaf(S, W.x, A.x); A.y = fmaf(S, W.y, A.y); \
  A.z = fmaf(S, W.z, A.z); A.w = fmaf(S, W.w, A.w);

__global__ __launch_bounds__(128) void k_proj(const float* __restrict__ f1,
    const float* __restrict__ f2, const float* __restrict__ f3,
    const float* __restrict__ f4, const float* __restrict__ W1,
    float* __restrict__ G, float* __restrict__ P){
  __shared__ __align__(16) float Fs[2][16*128];  // 2 x 8 KB
  __shared__ __align__(16) float Ws[2][16*64];   // 2 x 4 KB   -> 24 KB total
  const int img = blockIdx.y;
  const int u   = blockIdx.x;                  // 144 blocks/img, all equal work
  const float* feat; int C, HW, Woff, tile, split; long pbase; bool multi;
  if (u < 16)      { feat=f4; C=1024; HW=144;  Woff=896; tile=u>>3;      split=u&7;
                     pbase=P4_BASE + (long)split*P4_SLAB; multi=true;  }
  else if (u < 36) { feat=f3; C=512;  HW=576;  Woff=384; tile=(u-16)>>2; split=(u-16)&3;
                     pbase=P3_BASE + (long)split*P3_SLAB; multi=true;  }
  else if (u < 72) { feat=f2; C=256;  HW=2304; Woff=128; tile=(u-36)>>1; split=(u-36)&1;
                     pbase=P2_BASE + (long)split*P2_SLAB; multi=true;  }
  else             { feat=f1; C=128;  HW=9216; Woff=0;   tile=u-72;      split=0;
                     pbase=0; multi=false; }
  const int px0  = tile*128;
  const int hw4  = HW >> 2;
  const int px04 = px0 >> 2;
  const int tid  = threadIdx.x;
  const int jg   = tid & 7;         // j group: j = jg*8 + jj, jj=0..7
  const int pg   = tid >> 3;        // px group: px = px0 + pg*8 + p, p=0..7
  const int c0b  = split*128;
  const float4* feat4 = (const float4*)feat;
  const float4* W14   = (const float4*)W1;
  const long fbase = (long)img*C*hw4;
  float4 z = make_float4(0.f,0.f,0.f,0.f);
  float4 aA0=z,aA1=z,aA2=z,aA3=z,aA4=z,aA5=z,aA6=z,aA7=z;  // j jg*8..+3, px p=0..7
  float4 aB0=z,aB1=z,aB2=z,aB3=z,aB4=z,aB5=z,aB6=z,aB7=z;  // j jg*8+4..+7

  stage_chunk(feat4, W14, fbase, hw4, px04, Woff, c0b, tid,
              (float4*)Fs[0], (float4*)Ws[0]);
  __syncthreads();                               // drains vmcnt: buf0 ready
  for (int ch = 0; ch < 8; ch++){
    if (ch < 7)                                  // issue next chunk into buf^1
      stage_chunk(feat4, W14, fbase, hw4, px04, Woff, c0b + (ch+1)*16, tid,
                  (float4*)Fs[(ch+1)&1], (float4*)Ws[(ch+1)&1]);
    const float4* fsb = (const float4*)Fs[ch&1];
    const float4* wsb = (const float4*)Ws[ch&1];
    #pragma unroll 4
    for (int c = 0; c < 16; c++){
      float4 fa = fsb[c*32 + pg*2];        // px p=0..3   (8-lane broadcast)
      float4 fb = fsb[c*32 + pg*2 + 1];    // px p=4..7
      float4 wa = wsb[c*16 + jg*2];        // j jj=0..3   (2-way aliased: free)
      float4 wb = wsb[c*16 + jg*2 + 1];    // j jj=4..7
      FMA_Q(fa.x, wa, aA0) FMA_Q(fa.y, wa, aA1) FMA_Q(fa.z, wa, aA2) FMA_Q(fa.w, wa, aA3)
      FMA_Q(fb.x, wa, aA4) FMA_Q(fb.y, wa, aA5) FMA_Q(fb.z, wa, aA6) FMA_Q(fb.w, wa, aA7)
      FMA_Q(fa.x, wb, aB0) FMA_Q(fa.y, wb, aB1) FMA_Q(fa.z, wb, aB2) FMA_Q(fa.w, wb, aB3)
      FMA_Q(fb.x, wb, aB4) FMA_Q(fb.y, wb, aB5) FMA_Q(fb.z, wb, aB6) FMA_Q(fb.w, wb, aB7)
    }
    __syncthreads();                             // next-chunk loads drained + compute done
  }
  float* outb = multi ? (P + pbase + (long)img*HW*64)
                      : (G + (long)img*HW*64);           // L1 region starts at G+0
  const int pxa = px0 + pg*8;
#define STOREQ(A, B, PP) do { int gp = pxa + (PP); if (gp < HW){ \
    *(float4*)(outb + (long)gp*64 + jg*8) = A; \
    *(float4*)(outb + (long)gp*64 + jg*8 + 4) = B; } } while(0)
  STOREQ(aA0, aB0, 0); STOREQ(aA1, aB1, 1); STOREQ(aA2, aB2, 2); STOREQ(aA3, aB3, 3);
  STOREQ(aA4, aB4, 4); STOREQ(aA5, aB5, 5); STOREQ(aA6, aB6, 6); STOREQ(aA7, aB7, 7);
#undef STOREQ
}

// ---------------- K5b: sum split-K partial slabs into final G (L2-L4 region) ----
__global__ __launch_bounds__(256) void k_reduce(const float4* __restrict__ P4f,
                                                float4* __restrict__ G4f){
  const int N2 = P2_SLAB/4;   // 294912 f4
  const int N3 = P3_SLAB/4;   // 73728  f4
  const int N4 = P4_SLAB/4;   // 18432  f4
  int t = blockIdx.x*256 + threadIdx.x;
  if (t < N2){
    float4 a = P4f[t];
    float4 b = P4f[N2 + t];
    float4 r = make_float4(a.x+b.x, a.y+b.y, a.z+b.z, a.w+b.w);
    G4f[G2_OFF/4 + t] = r;
  } else if (t < N2 + N3){
    int u = t - N2;
    const float4* base = P4f + P3_BASE/4 + u;
    float4 r = base[0];
    #pragma unroll
    for (int s = 1; s < 4; s++){
      float4 b = base[(long)s*N3];
      r.x += b.x; r.y += b.y; r.z += b.z; r.w += b.w;
    }
    G4f[G3_OFF/4 + u] = r;
  } else if (t < N2 + N3 + N4){
    int u = t - N2 - N3;
    const float4* base = P4f + P4_BASE/4 + u;
    float4 r = base[0];
    #pragma unroll
    for (int s = 1; s < 8; s++){
      float4 b = base[(long)s*N4];
      r.x += b.x; r.y += b.y; r.z += b.z; r.w += b.w;
    }
    G4f[G4_OFF/4 + u] = r;
  }
}

// ---------------- K6: fused ROI-gather + bias + leaky + layer2 + assembly ----------------
__device__ __forceinline__ void roi_level(const float* __restrict__ g,
    int Hl, int Wl, float scale, float x1, float y1, float x2, float y2,
    int lane, float& h){
  float bx1=x1*scale, by1=y1*scale, bx2=x2*scale, by2=y2*scale;
  float rw=fmaxf(bx2-bx1,1.f), rh=fmaxf(by2-by1,1.f);
  float ys[2]={by1+rh*0.25f, by1+rh*0.75f};
  float xs[2]={bx1+rw*0.25f, bx1+rw*0.75f};
  #pragma unroll
  for (int pt = 0; pt < 4; pt++){
    float y=ys[pt>>1], x=xs[pt&1];
    if ((y>-1.f)&&(y<(float)Hl)&&(x>-1.f)&&(x<(float)Wl)){   // wave-uniform branch
      float yc=fmaxf(y,0.f), xc=fmaxf(x,0.f);
      int y0=(int)fminf(floorf(yc),(float)(Hl-1));
      int x0=(int)fminf(floorf(xc),(float)(Wl-1));
      int y1i=min(y0+1,Hl-1), x1i=min(x0+1,Wl-1);
      float ly=yc-(float)y0, lx=xc-(float)x0;
      float hy=1.f-ly, hx=1.f-lx;
      h += (hy*hx*0.25f)*g[(long)(y0*Wl+x0)*64+lane];
      h += (hy*lx*0.25f)*g[(long)(y0*Wl+x1i)*64+lane];
      h += (ly*hx*0.25f)*g[(long)(y1i*Wl+x0)*64+lane];
      h += (ly*lx*0.25f)*g[(long)(y1i*Wl+x1i)*64+lane];
    }
  }
}

__global__ __launch_bounds__(256) void k_roi_mlp(const float* __restrict__ G,
    const float* __restrict__ selbox, const u32* __restrict__ selcnt,
    const float* __restrict__ b1, const float* __restrict__ W2,
    const float* __restrict__ b2, float* __restrict__ out){
  const int img  = blockIdx.y;
  const int wave = threadIdx.x >> 6;
  const int lane = threadIdx.x & 63;
  const int slot = blockIdx.x*4 + wave;
  if (slot >= MAXDET) return;
  float* o = out + ((long)img*MAXDET + slot)*68;
  if (slot >= (int)selcnt[img]){
    o[4+lane] = 0.f;
    if (lane < 4) o[lane] = 0.f;
    return;
  }
  const float* sb = selbox + ((long)img*MAXDET + slot)*4;
  float x1 = sb[0], y1 = sb[1], x2 = sb[2], y2 = sb[3];
  const float* Gi1 = G +          (long)img*9216*64;
  const float* Gi2 = G + G2_OFF + (long)img*2304*64;
  const float* Gi3 = G + G3_OFF + (long)img*576*64;
  const float* Gi4 = G + G4_OFF + (long)img*144*64;
  float h = 0.f;
  roi_level(Gi1, 96, 96, 0.125f,    x1,y1,x2,y2, lane, h);
  roi_level(Gi2, 48, 48, 0.0625f,   x1,y1,x2,y2, lane, h);
  roi_level(Gi3, 24, 24, 0.03125f,  x1,y1,x2,y2, lane, h);
  roi_level(Gi4, 12, 12, 0.015625f, x1,y1,x2,y2, lane, h);
  float h1 = leaky(h + b1[lane]);
  float c = 0.f;
  #pragma unroll 8
  for (int k = 0; k < 64; k++){
    float hk = __shfl(h1, k, 64);
    c += hk * W2[k*64 + lane];
  }
  o[4+lane] = leaky(c + b2[lane]);
  if (lane < 4) o[lane] = sb[lane] / 768.0f;
}

// ---------------- workspace layout (bytes) ----------------
// 0        hist    u32[8][2048]        65536
// 65536    cnt     u32[8]              256 (padded)
// 65792    kmask   u64[8][8]           512
// 66304    thr     u32[8]              256
// 66560    selbox  f32[8][300][4]      38400
// 104960   selcnt  u32[8]              256
// 105216   sbits   u32[8][36720]       1175040
// 1280256  cls     i32[8][36720]       1175040
// 2455296  cand    u64[8][1024]        65536
// 2520832  cbs_g   f4[8][512]          65536
// 2586368  obs_g   f4[8][512]          65536
// 2651904  lrows_g u64[8][512][8]      262144
// 2914048  G       f32 level-major     25067520
// 27981568 P       f32 partials        16515072   -> total ~44.5 MB
#define WS_G 2914048
#define WS_P 27981568

extern "C" void kernel_launch(void* const* d_in, const int* in_sizes, int n_in,
                              void* d_out, int out_size, void* d_ws, size_t ws_size,
                              hipStream_t stream){
  const float* preds = (const float*)d_in[0];
  const float* f1 = (const float*)d_in[1];
  const float* f2 = (const float*)d_in[2];
  const float* f3 = (const float*)d_in[3];
  const float* f4 = (const float*)d_in[4];
  const float* W1 = (const float*)d_in[5];
  const float* b1 = (const float*)d_in[6];
  const float* W2 = (const float*)d_in[7];
  const float* b2 = (const float*)d_in[8];
  float* out = (float*)d_out;
  char* ws = (char*)d_ws;
  u32* hist    = (u32*)(ws + 0);
  u32* cnt     = (u32*)(ws + 65536);
  u64* kmask_g = (u64*)(ws + 65792);
  u32* thr     = (u32*)(ws + 66304);
  float* selb  = (float*)(ws + 66560);
  u32* selc    = (u32*)(ws + 104960);
  u32* sbits   = (u32*)(ws + 105216);
  int* clsA    = (int*)(ws + 1280256);
  u64* cand    = (u64*)(ws + 2455296);
  float4* cbs_g = (float4*)(ws + 2520832);
  float4* obs_g = (float4*)(ws + 2586368);
  u64* lrows_g  = (u64*)(ws + 2651904);
  float* G     = (float*)(ws + WS_G);
  float* P     = (float*)(ws + WS_P);

  hipMemsetAsync(ws, 0, 66304, stream);                 // hist + cnt + kmask

  dim3 gs((NCAND + 255)/256, B_IMG);
  k_score<<<gs, 256, 0, stream>>>(preds, sbits, clsA, hist);
  k_thresh<<<B_IMG, 64, 0, stream>>>(hist, thr);
  dim3 g3((NCAND+255)/256, B_IMG);
  k_gather<<<g3, 256, 0, stream>>>(sbits, thr, cnt, cand);
  k_rank<<<B_IMG*4, 256, 0, stream>>>(preds, clsA, cand, cnt, cbs_g, obs_g, kmask_g);
  k_iou<<<B_IMG*8, 512, 0, stream>>>(cbs_g, kmask_g, lrows_g);
  k_greedy<<<B_IMG, 512, 0, stream>>>(lrows_g, kmask_g, obs_g, selb, selc);
  k_proj<<<dim3(144, B_IMG), 128, 0, stream>>>(f1, f2, f3, f4, W1, G, P);
  // reduce L2-L4 partial slabs into final G: (294912+73728+18432) f4 / 256
  k_reduce<<<1512, 256, 0, stream>>>((const float4*)P, (float4*)G);
  k_roi_mlp<<<dim3((MAXDET+3)/4, B_IMG), 256, 0, stream>>>(G, selb, selc, b1, W2, b2, out);
}